// Round 2
// baseline (2168.429 us; speedup 1.0000x reference)
//
#include <hip/hip_runtime.h>
#include <hip/hip_bf16.h>

typedef unsigned int u32;
typedef unsigned short u16;
typedef __attribute__((ext_vector_type(4))) float f32x4;
typedef __attribute__((ext_vector_type(8))) short s16x8;
typedef __attribute__((ext_vector_type(4))) u16 u16x4;
typedef __attribute__((ext_vector_type(8))) u16 u16x8;

#define DEVFN __device__ __forceinline__

DEVFN u16 f2bf(float f) {
  u32 x = __builtin_bit_cast(u32, f);
  u32 r = x + 0x7fffu + ((x >> 16) & 1u);   // round-to-nearest-even
  return (u16)(r >> 16);
}

DEVFN void gload_lds16(const u16* g, u16* l) {
  __builtin_amdgcn_global_load_lds((const __attribute__((address_space(1))) u32*)g,
                                   (__attribute__((address_space(3))) u32*)l, 16, 0, 0);
}

// ---------------------------------------------------------------------------
// Generic bf16 MFMA GEMM:  C[M,N] = A[M,K] @ Bt[N,K]^T  (+ epilogue by MODE)
// 128x128 tile, BK=64, 4 waves (2x2 of 64x64), m97 structure.
// MODE 0: bf16 C = relu(acc + bias[n])            (GEMM1 -> h)
// MODE 1: bf16 C = acc + bias[n]                  (K/Q/V)
// MODE 2: f32  C = acc * scale                    (QK^T -> scores, batched)
// MODE 3: bf16 C = acc                            (PV -> o, batched, row guard)
// MODE 4: f32  C = acc + bias[n] + resid[ci]      (GEMM2 -> y)
// ---------------------------------------------------------------------------
template<int MODE>
__launch_bounds__(256)
__global__ void gemm_bt(const u16* __restrict__ Ag, int lda, int aRPB, int aRowMax,
                        const u16* __restrict__ Bg, int ldb, int bRPB, int bRowMax,
                        void* __restrict__ Cptr, int ldc, int cRPB, int cRowGuard,
                        const float* __restrict__ bias, const float* __restrict__ resid,
                        int K, float scale) {
  __shared__ __align__(16) u16 As[128 * 64];
  __shared__ __align__(16) u16 Bs[128 * 64];
  const int tid = threadIdx.x;
  const int lane = tid & 63, wid = tid >> 6;
  const int l15 = lane & 15, l4 = lane >> 4;
  const int wr = wid >> 1, wc = wid & 1;
  const int m0 = blockIdx.x * 128, n0 = blockIdx.y * 128;
  const int b = blockIdx.z;

  const u16* aSrc[4];
  const u16* bSrc[4];
  u16* aDst[4];
  u16* bDst[4];
#pragma unroll
  for (int i = 0; i < 4; ++i) {
    int c = i * 256 + tid;
    int r = c >> 3, g = c & 7;
    long arow = (long)b * aRPB + m0 + r; if (arow > aRowMax) arow = aRowMax;
    aSrc[i] = Ag + arow * (long)lda + g * 8;
    aDst[i] = &As[c * 8];
    long brow = (long)b * bRPB + n0 + r; if (brow > bRowMax) brow = bRowMax;
    bSrc[i] = Bg + brow * (long)ldb + g * 8;
    bDst[i] = &Bs[c * 8];
  }

  f32x4 acc[4][4];
#pragma unroll
  for (int i = 0; i < 4; ++i)
#pragma unroll
    for (int j = 0; j < 4; ++j) acc[i][j] = (f32x4){0.f, 0.f, 0.f, 0.f};

  for (int kt = 0; kt < K; kt += 64) {
#pragma unroll
    for (int i = 0; i < 4; ++i) gload_lds16(aSrc[i] + kt, aDst[i]);
#pragma unroll
    for (int i = 0; i < 4; ++i) gload_lds16(bSrc[i] + kt, bDst[i]);
    __syncthreads();   // emits vmcnt(0) drain of global_load_lds
#pragma unroll
    for (int kk = 0; kk < 2; ++kk) {
      s16x8 af[4], bfr[4];
#pragma unroll
      for (int mi = 0; mi < 4; ++mi) {
        int rr = wr * 64 + mi * 16 + l15;
        af[mi] = *(const s16x8*)&As[rr * 64 + kk * 32 + l4 * 8];
      }
#pragma unroll
      for (int ni = 0; ni < 4; ++ni) {
        int rr = wc * 64 + ni * 16 + l15;
        bfr[ni] = *(const s16x8*)&Bs[rr * 64 + kk * 32 + l4 * 8];
      }
#pragma unroll
      for (int mi = 0; mi < 4; ++mi)
#pragma unroll
        for (int ni = 0; ni < 4; ++ni)
          acc[mi][ni] = __builtin_amdgcn_mfma_f32_16x16x32_bf16(af[mi], bfr[ni], acc[mi][ni], 0, 0, 0);
    }
    __syncthreads();
  }

  const long cRow0 = (long)b * cRPB + m0;
#pragma unroll
  for (int mi = 0; mi < 4; ++mi) {
#pragma unroll
    for (int ni = 0; ni < 4; ++ni) {
      const int n = n0 + wc * 64 + ni * 16 + l15;
      float bv = 0.f;
      if (MODE == 0 || MODE == 1 || MODE == 4) bv = bias[n];
#pragma unroll
      for (int r = 0; r < 4; ++r) {
        const int s = wr * 64 + mi * 16 + l4 * 4 + r;   // C/D map: row=4*(l>>4)+reg
        if (m0 + s >= cRowGuard) continue;
        const long ci = (cRow0 + s) * (long)ldc + n;
        float v = acc[mi][ni][r];
        if (MODE == 0)      { v += bv; v = v > 0.f ? v : 0.f; ((u16*)Cptr)[ci] = f2bf(v); }
        else if (MODE == 1) { v += bv; ((u16*)Cptr)[ci] = f2bf(v); }
        else if (MODE == 2) { ((float*)Cptr)[ci] = v * scale; }
        else if (MODE == 3) { ((u16*)Cptr)[ci] = f2bf(v); }
        else                { ((float*)Cptr)[ci] = v + bv + resid[ci]; }
      }
    }
  }
}

// masked row softmax over scores[CH][128][128] -> P bf16 [CH][128][128]
__launch_bounds__(256)
__global__ void softmax_rows(const float* __restrict__ S, u16* __restrict__ P) {
  const int wid = threadIdx.x >> 6, lane = threadIdx.x & 63;
  const long rowg = (long)blockIdx.x * 4 + wid;
  const int i = (int)(rowg & 127);
  const float* srow = S + rowg * 128;
  u16* prow = P + rowg * 128;
  if (i >= 100) { prow[lane] = 0; prow[lane + 64] = 0; return; }
  const int jmax = (i + 1 < 99) ? i + 1 : 99;          // tril(k=1): j <= i+1, j < 100
  float s0 = srow[lane], s1 = srow[lane + 64];
  bool v0 = lane <= jmax, v1 = (lane + 64) <= jmax;
  float m = fmaxf(v0 ? s0 : -3e38f, v1 ? s1 : -3e38f);
#pragma unroll
  for (int off = 32; off; off >>= 1) m = fmaxf(m, __shfl_xor(m, off));
  float e0 = v0 ? __expf(s0 - m) : 0.f;
  float e1 = v1 ? __expf(s1 - m) : 0.f;
  float sum = e0 + e1;
#pragma unroll
  for (int off = 32; off; off >>= 1) sum += __shfl_xor(sum, off);
  float rs = 1.f / sum;
  prow[lane] = f2bf(e0 * rs);
  prow[lane + 64] = f2bf(e1 * rs);
}

// transpose-cast fp32 W[K][N] -> bf16 Wt[N][K]
__launch_bounds__(256)
__global__ void transpose_cast_w(const float* __restrict__ W, u16* __restrict__ Wt,
                                 int K, int N) {
  __shared__ __align__(16) float t[64][68];
  const int tid = threadIdx.x;
  const int n0 = blockIdx.x * 64, k0 = blockIdx.y * 64;
#pragma unroll
  for (int it = 0; it < 4; ++it) {
    int c = it * 256 + tid;
    int r = c >> 4, cc = (c & 15) * 4;
    f32x4 v = *(const f32x4*)&W[(long)(k0 + r) * N + n0 + cc];
    *(f32x4*)&t[r][cc] = v;
  }
  __syncthreads();
#pragma unroll
  for (int it = 0; it < 4; ++it) {
    int c = it * 256 + tid;
    int n = c >> 4, kk = (c & 15) * 4;
    u16x4 o;
#pragma unroll
    for (int j = 0; j < 4; ++j) o[j] = f2bf(t[kk + j][n]);
    *(u16x4*)&Wt[(long)(n0 + n) * K + k0 + kk] = o;
  }
}

__launch_bounds__(256)
__global__ void cast_f32_to_bf16(const float* __restrict__ in, u16* __restrict__ out, long n4) {
  for (long i = (long)blockIdx.x * 256 + threadIdx.x; i < n4; i += (long)gridDim.x * 256) {
    f32x4 v = *(const f32x4*)&in[i * 4];
    u16x4 o;
#pragma unroll
    for (int j = 0; j < 4; ++j) o[j] = f2bf(v[j]);
    *(u16x4*)&out[i * 4] = o;
  }
}

// V [CH*100][2048] bf16 -> Vt [CH][2048][128] bf16 (zero-padded s>=100)
__launch_bounds__(256)
__global__ void transpose_v64(const u16* __restrict__ V, u16* __restrict__ Vt) {
  __shared__ __align__(16) u16 t[64][72];
  const int tid = threadIdx.x;
  const int h0 = blockIdx.x * 64, s0 = blockIdx.y * 64, b = blockIdx.z;
#pragma unroll
  for (int it = 0; it < 2; ++it) {
    int c = it * 256 + tid;
    int s = c >> 3, hh = (c & 7) * 8;
    u16x8 v = {0, 0, 0, 0, 0, 0, 0, 0};
    if (s0 + s < 100) v = *(const u16x8*)&V[((long)b * 100 + s0 + s) * 2048 + h0 + hh];
    *(u16x8*)&t[s][hh] = v;
  }
  __syncthreads();
#pragma unroll
  for (int it = 0; it < 2; ++it) {
    int c = it * 256 + tid;
    int h = c >> 3, ss = (c & 7) * 8;
    u16x8 o;
#pragma unroll
    for (int j = 0; j < 8; ++j) o[j] = t[ss + j][h];
    *(u16x8*)&Vt[((long)b * 2048 + h0 + h) * 128 + s0 + ss] = o;
  }
}

__launch_bounds__(256)
__global__ void ln_stats(const float* __restrict__ y, float* __restrict__ stats) {
  __shared__ float rs[256], rq[256];
  const int b = blockIdx.x, tid = threadIdx.x;
  const float* yb = y + (long)b * 51200;
  float s = 0.f, q = 0.f;
  for (int i = tid; i < 51200; i += 256) { float v = yb[i]; s += v; q += v * v; }
  rs[tid] = s; rq[tid] = q;
  __syncthreads();
  for (int off = 128; off; off >>= 1) {
    if (tid < off) { rs[tid] += rs[tid + off]; rq[tid] += rq[tid + off]; }
    __syncthreads();
  }
  if (tid == 0) {
    float mean = rs[0] * (1.f / 51200.f);
    float var = rq[0] * (1.f / 51200.f) - mean * mean;
    stats[b * 2] = mean;
    stats[b * 2 + 1] = rsqrtf(var + 1e-5f);
  }
}

__launch_bounds__(256)
__global__ void ln_apply(float* __restrict__ y, const float* __restrict__ stats) {
  const long i4 = (long)blockIdx.x * 256 + threadIdx.x;  // < 3276800
  const int b = (int)(i4 / 12800);
  float mu = stats[b * 2], rstd = stats[b * 2 + 1];
  f32x4 v = *(const f32x4*)&y[i4 * 4];
#pragma unroll
  for (int j = 0; j < 4; ++j) v[j] = (v[j] - mu) * rstd;
  *(f32x4*)&y[i4 * 4] = v;
}

extern "C" void kernel_launch(void* const* d_in, const int* in_sizes, int n_in,
                              void* d_out, int out_size, void* d_ws, size_t ws_size,
                              hipStream_t stream) {
  const float* x    = (const float*)d_in[0];
  const float* W_w  = (const float*)d_in[1];
  const float* W_b  = (const float*)d_in[2];
  const float* WK_w = (const float*)d_in[3];
  const float* WK_b = (const float*)d_in[4];
  const float* WQ_w = (const float*)d_in[5];
  const float* WQ_b = (const float*)d_in[6];
  const float* WV_w = (const float*)d_in[7];
  const float* WV_b = (const float*)d_in[8];
  const float* W2_w = (const float*)d_in[9];
  const float* W2_b = (const float*)d_in[10];
  float* out = (float*)d_out;

  // ---- workspace-adaptive batch chunking (crash fix: never exceed ws_size) ----
  // fixed: xb 26,214,400 + W1t 2,097,152 + WK/WQ/WVt 3*8,388,608 + W2t 2,097,152
  //        + stats 2048 + alignment slack
  const size_t FIXED = 26214400ull + 2097152ull + 3ull * 8388608ull + 2097152ull + 65536ull;
  // per-batch: h/K/Q/V 4*409,600 + sc 65,536 + P 32,768 + Vt 524,288 = 2,260,992
  const size_t PERB = 2260992ull;
  int CH = 256;
  if (ws_size == 0) CH = 32;
  else { while (CH > 4 && FIXED + (size_t)CH * PERB + 4096 > ws_size) CH >>= 1; }
  const int NCH = 256 / CH;
  const int CHR = CH * 100;                    // rows per chunk
  const int GX = (CHR + 127) / 128;            // M-tiles per chunk

  char* p = (char*)d_ws;
  auto carve = [&](size_t bytes) { char* r = p; p += (bytes + 255) & ~(size_t)255; return r; };
  u16* xb   = (u16*)carve(26214400);                  // x bf16 [25600][512]
  u16* W1t  = (u16*)carve(2097152);                   // [2048][512]
  u16* WKt  = (u16*)carve(8388608);                   // [2048][2048]
  u16* WQt  = (u16*)carve(8388608);
  u16* WVt  = (u16*)carve(8388608);
  u16* W2t  = (u16*)carve(2097152);                   // [512][2048]
  float* stats = (float*)carve(2048);
  u16* h    = (u16*)carve((size_t)CH * 409600);       // h bf16 [CHR][2048]; reused as o
  u16* Kc   = (u16*)carve((size_t)CH * 409600);
  u16* Qc   = (u16*)carve((size_t)CH * 409600);
  u16* Vc   = (u16*)carve((size_t)CH * 409600);
  float* sc = (float*)carve((size_t)CH * 65536);      // scores f32 [CH][128][128]
  u16* P    = (u16*)carve((size_t)CH * 32768);        // P bf16 [CH][128][128]
  u16* Vt   = (u16*)carve((size_t)CH * 524288);       // [CH][2048][128]

  cast_f32_to_bf16<<<2048, 256, 0, stream>>>(x, xb, 3276800);
  transpose_cast_w<<<dim3(32, 8),  256, 0, stream>>>(W_w,  W1t, 512, 2048);
  transpose_cast_w<<<dim3(32, 32), 256, 0, stream>>>(WK_w, WKt, 2048, 2048);
  transpose_cast_w<<<dim3(32, 32), 256, 0, stream>>>(WQ_w, WQt, 2048, 2048);
  transpose_cast_w<<<dim3(32, 32), 256, 0, stream>>>(WV_w, WVt, 2048, 2048);
  transpose_cast_w<<<dim3(8, 32),  256, 0, stream>>>(W2_w, W2t, 2048, 512);

  for (int c = 0; c < NCH; ++c) {
    const u16* xc = xb + (size_t)c * CHR * 512;
    const float* xf = x + (size_t)c * CHR * 512;
    float* outc = out + (size_t)c * CHR * 512;

    // h = relu(xc @ W + b)   M=CHR N=2048 K=512
    gemm_bt<0><<<dim3(GX, 16, 1), 256, 0, stream>>>(xc, 512, 0, CHR - 1, W1t, 512, 0, 2047,
                                                    h, 2048, 0, CHR, W_b, nullptr, 512, 1.f);
    // K,Q,V = h @ W* + b*   M=CHR N=2048 K=2048
    gemm_bt<1><<<dim3(GX, 16, 1), 256, 0, stream>>>(h, 2048, 0, CHR - 1, WKt, 2048, 0, 2047,
                                                    Kc, 2048, 0, CHR, WK_b, nullptr, 2048, 1.f);
    gemm_bt<1><<<dim3(GX, 16, 1), 256, 0, stream>>>(h, 2048, 0, CHR - 1, WQt, 2048, 0, 2047,
                                                    Qc, 2048, 0, CHR, WQ_b, nullptr, 2048, 1.f);
    gemm_bt<1><<<dim3(GX, 16, 1), 256, 0, stream>>>(h, 2048, 0, CHR - 1, WVt, 2048, 0, 2047,
                                                    Vc, 2048, 0, CHR, WV_b, nullptr, 2048, 1.f);
    // scores[b] = Q[b] @ K[b]^T / sqrt(512)   batched over CH
    gemm_bt<2><<<dim3(1, 1, CH), 256, 0, stream>>>(Qc, 2048, 100, CHR - 1, Kc, 2048, 100, CHR - 1,
                                                   sc, 128, 128, 1 << 30, nullptr, nullptr,
                                                   2048, 0.044194173824159216f);
    softmax_rows<<<CH * 32, 256, 0, stream>>>(sc, P);
    transpose_v64<<<dim3(32, 2, CH), 256, 0, stream>>>(Vc, Vt);
    // o[b] = P[b] @ Vt[b]^T   batched, N=2048, K=128 (o overwrites h)
    gemm_bt<3><<<dim3(1, 16, CH), 256, 0, stream>>>(P, 128, 128, CH * 128 - 1, Vt, 128, 2048,
                                                    CH * 2048 - 1, h, 2048, 100, 100,
                                                    nullptr, nullptr, 128, 1.f);
    // y = o @ W2 + b2 + x   M=CHR N=512 K=2048  (f32 out)
    gemm_bt<4><<<dim3(GX, 4, 1), 256, 0, stream>>>(h, 2048, 0, CHR - 1, W2t, 2048, 0, 511,
                                                   outc, 512, 0, CHR, W2_b, xf, 2048, 1.f);
  }

  ln_stats<<<256, 256, 0, stream>>>(out, stats);
  ln_apply<<<12800, 256, 0, stream>>>(out, stats);
}

// Round 3
// 1939.755 us; speedup vs baseline: 1.1179x; 1.1179x over previous
//
#include <hip/hip_runtime.h>
#include <hip/hip_bf16.h>

typedef unsigned int u32;
typedef unsigned short u16;
typedef __attribute__((ext_vector_type(4))) float f32x4;
typedef __attribute__((ext_vector_type(8))) short s16x8;
typedef __attribute__((ext_vector_type(4))) u16 u16x4;
typedef __attribute__((ext_vector_type(8))) u16 u16x8;

#define DEVFN __device__ __forceinline__

DEVFN u16 f2bf(float f) {
  u32 x = __builtin_bit_cast(u32, f);
  u32 r = x + 0x7fffu + ((x >> 16) & 1u);   // round-to-nearest-even
  return (u16)(r >> 16);
}

DEVFN void gload_lds16(const u16* g, u16* l) {
  __builtin_amdgcn_global_load_lds((const __attribute__((address_space(1))) u32*)g,
                                   (__attribute__((address_space(3))) u32*)l, 16, 0, 0);
}

// ---------------------------------------------------------------------------
// Generic bf16 MFMA GEMM:  C[M,N] = A[M,K] @ Bt[N,K]^T  (+ epilogue by MODE)
// 128x128 tile, BK=64, 4 waves (2x2 of 64x64), m97 structure.
// MODE 0: bf16 C = relu(acc + bias[n])            (GEMM1 -> h)
// MODE 1: bf16 C = acc + bias[n]                  (fused KQV)
// MODE 2: f32  C = acc * scale                    (QK^T -> scores, batched)
// MODE 3: bf16 C = acc                            (PV -> o, batched, row guard)
// MODE 4: f32  C = acc + bias[n] + resid[ci]      (GEMM2 -> y)
// ---------------------------------------------------------------------------
template<int MODE>
__launch_bounds__(256)
__global__ void gemm_bt(const u16* __restrict__ Ag, int lda, int aRPB, int aRowMax,
                        const u16* __restrict__ Bg, int ldb, int bRPB, int bRowMax,
                        void* __restrict__ Cptr, int ldc, int cRPB, int cRowGuard,
                        const float* __restrict__ bias, const float* __restrict__ resid,
                        int K, float scale) {
  __shared__ __align__(16) u16 As[128 * 64];
  __shared__ __align__(16) u16 Bs[128 * 64];
  const int tid = threadIdx.x;
  const int lane = tid & 63, wid = tid >> 6;
  const int l15 = lane & 15, l4 = lane >> 4;
  const int wr = wid >> 1, wc = wid & 1;
  const int m0 = blockIdx.x * 128, n0 = blockIdx.y * 128;
  const int b = blockIdx.z;

  const u16* aSrc[4];
  const u16* bSrc[4];
  u16* aDst[4];
  u16* bDst[4];
#pragma unroll
  for (int i = 0; i < 4; ++i) {
    int c = i * 256 + tid;
    int r = c >> 3, g = c & 7;
    long arow = (long)b * aRPB + m0 + r; if (arow > aRowMax) arow = aRowMax;
    aSrc[i] = Ag + arow * (long)lda + g * 8;
    aDst[i] = &As[c * 8];
    long brow = (long)b * bRPB + n0 + r; if (brow > bRowMax) brow = bRowMax;
    bSrc[i] = Bg + brow * (long)ldb + g * 8;
    bDst[i] = &Bs[c * 8];
  }

  f32x4 acc[4][4];
#pragma unroll
  for (int i = 0; i < 4; ++i)
#pragma unroll
    for (int j = 0; j < 4; ++j) acc[i][j] = (f32x4){0.f, 0.f, 0.f, 0.f};

  for (int kt = 0; kt < K; kt += 64) {
#pragma unroll
    for (int i = 0; i < 4; ++i) gload_lds16(aSrc[i] + kt, aDst[i]);
#pragma unroll
    for (int i = 0; i < 4; ++i) gload_lds16(bSrc[i] + kt, bDst[i]);
    __syncthreads();   // emits vmcnt(0) drain of global_load_lds
#pragma unroll
    for (int kk = 0; kk < 2; ++kk) {
      s16x8 af[4], bfr[4];
#pragma unroll
      for (int mi = 0; mi < 4; ++mi) {
        int rr = wr * 64 + mi * 16 + l15;
        af[mi] = *(const s16x8*)&As[rr * 64 + kk * 32 + l4 * 8];
      }
#pragma unroll
      for (int ni = 0; ni < 4; ++ni) {
        int rr = wc * 64 + ni * 16 + l15;
        bfr[ni] = *(const s16x8*)&Bs[rr * 64 + kk * 32 + l4 * 8];
      }
#pragma unroll
      for (int mi = 0; mi < 4; ++mi)
#pragma unroll
        for (int ni = 0; ni < 4; ++ni)
          acc[mi][ni] = __builtin_amdgcn_mfma_f32_16x16x32_bf16(af[mi], bfr[ni], acc[mi][ni], 0, 0, 0);
    }
    __syncthreads();
  }

  const long cRow0 = (long)b * cRPB + m0;
#pragma unroll
  for (int mi = 0; mi < 4; ++mi) {
#pragma unroll
    for (int ni = 0; ni < 4; ++ni) {
      const int n = n0 + wc * 64 + ni * 16 + l15;
      float bv = 0.f;
      if (MODE == 0 || MODE == 1 || MODE == 4) bv = bias[n];
#pragma unroll
      for (int r = 0; r < 4; ++r) {
        const int s = wr * 64 + mi * 16 + l4 * 4 + r;   // C/D map: row=4*(l>>4)+reg
        if (m0 + s >= cRowGuard) continue;
        const long ci = (cRow0 + s) * (long)ldc + n;
        float v = acc[mi][ni][r];
        if (MODE == 0)      { v += bv; v = v > 0.f ? v : 0.f; ((u16*)Cptr)[ci] = f2bf(v); }
        else if (MODE == 1) { v += bv; ((u16*)Cptr)[ci] = f2bf(v); }
        else if (MODE == 2) { ((float*)Cptr)[ci] = v * scale; }
        else if (MODE == 3) { ((u16*)Cptr)[ci] = f2bf(v); }
        else                { ((float*)Cptr)[ci] = v + bv + resid[ci]; }
      }
    }
  }
}

// masked row softmax over scores[CH][128][128] -> P bf16 [CH][128][128]
__launch_bounds__(256)
__global__ void softmax_rows(const float* __restrict__ S, u16* __restrict__ P) {
  const int wid = threadIdx.x >> 6, lane = threadIdx.x & 63;
  const long rowg = (long)blockIdx.x * 4 + wid;
  const int i = (int)(rowg & 127);
  const float* srow = S + rowg * 128;
  u16* prow = P + rowg * 128;
  if (i >= 100) { prow[lane] = 0; prow[lane + 64] = 0; return; }
  const int jmax = (i + 1 < 99) ? i + 1 : 99;          // tril(k=1): j <= i+1, j < 100
  float s0 = srow[lane], s1 = srow[lane + 64];
  bool v0 = lane <= jmax, v1 = (lane + 64) <= jmax;
  float m = fmaxf(v0 ? s0 : -3e38f, v1 ? s1 : -3e38f);
#pragma unroll
  for (int off = 32; off; off >>= 1) m = fmaxf(m, __shfl_xor(m, off));
  float e0 = v0 ? __expf(s0 - m) : 0.f;
  float e1 = v1 ? __expf(s1 - m) : 0.f;
  float sum = e0 + e1;
#pragma unroll
  for (int off = 32; off; off >>= 1) sum += __shfl_xor(sum, off);
  float rs = 1.f / sum;
  prow[lane] = f2bf(e0 * rs);
  prow[lane + 64] = f2bf(e1 * rs);
}

// transpose-cast fp32 W[K][N] -> bf16 Wt[N][K]
__launch_bounds__(256)
__global__ void transpose_cast_w(const float* __restrict__ W, u16* __restrict__ Wt,
                                 int K, int N) {
  __shared__ __align__(16) float t[64][68];
  const int tid = threadIdx.x;
  const int n0 = blockIdx.x * 64, k0 = blockIdx.y * 64;
#pragma unroll
  for (int it = 0; it < 4; ++it) {
    int c = it * 256 + tid;
    int r = c >> 4, cc = (c & 15) * 4;
    f32x4 v = *(const f32x4*)&W[(long)(k0 + r) * N + n0 + cc];
    *(f32x4*)&t[r][cc] = v;
  }
  __syncthreads();
#pragma unroll
  for (int it = 0; it < 4; ++it) {
    int c = it * 256 + tid;
    int n = c >> 4, kk = (c & 15) * 4;
    u16x4 o;
#pragma unroll
    for (int j = 0; j < 4; ++j) o[j] = f2bf(t[kk + j][n]);
    *(u16x4*)&Wt[(long)(n0 + n) * K + k0 + kk] = o;
  }
}

__launch_bounds__(256)
__global__ void cast_f32_to_bf16(const float* __restrict__ in, u16* __restrict__ out, long n4) {
  for (long i = (long)blockIdx.x * 256 + threadIdx.x; i < n4; i += (long)gridDim.x * 256) {
    f32x4 v = *(const f32x4*)&in[i * 4];
    u16x4 o;
#pragma unroll
    for (int j = 0; j < 4; ++j) o[j] = f2bf(v[j]);
    *(u16x4*)&out[i * 4] = o;
  }
}

// concat 3x2048 f32 bias vectors -> one [6144]
__launch_bounds__(256)
__global__ void concat_bias(const float* __restrict__ a, const float* __restrict__ b,
                            const float* __restrict__ c, float* __restrict__ o) {
  int i = blockIdx.x * 256 + threadIdx.x;   // < 6144
  o[i] = i < 2048 ? a[i] : (i < 4096 ? b[i - 2048] : c[i - 4096]);
}

// V view [CH*100][vstride] bf16 -> Vt [CH][2048][128] bf16 (zero-padded s>=100)
__launch_bounds__(256)
__global__ void transpose_v64(const u16* __restrict__ V, u16* __restrict__ Vt, int vstride) {
  __shared__ __align__(16) u16 t[64][72];
  const int tid = threadIdx.x;
  const int h0 = blockIdx.x * 64, s0 = blockIdx.y * 64, b = blockIdx.z;
#pragma unroll
  for (int it = 0; it < 2; ++it) {
    int c = it * 256 + tid;
    int s = c >> 3, hh = (c & 7) * 8;
    u16x8 v = {0, 0, 0, 0, 0, 0, 0, 0};
    if (s0 + s < 100) v = *(const u16x8*)&V[((long)b * 100 + s0 + s) * vstride + h0 + hh];
    *(u16x8*)&t[s][hh] = v;
  }
  __syncthreads();
#pragma unroll
  for (int it = 0; it < 2; ++it) {
    int c = it * 256 + tid;
    int h = c >> 3, ss = (c & 7) * 8;
    u16x8 o;
#pragma unroll
    for (int j = 0; j < 8; ++j) o[j] = t[ss + j][h];
    *(u16x8*)&Vt[((long)b * 2048 + h0 + h) * 128 + s0 + ss] = o;
  }
}

__launch_bounds__(256)
__global__ void ln_stats(const float* __restrict__ y, float* __restrict__ stats) {
  __shared__ float rs[256], rq[256];
  const int b = blockIdx.x, tid = threadIdx.x;
  const float* yb = y + (long)b * 51200;
  float s = 0.f, q = 0.f;
  for (int i = tid; i < 51200; i += 256) { float v = yb[i]; s += v; q += v * v; }
  rs[tid] = s; rq[tid] = q;
  __syncthreads();
  for (int off = 128; off; off >>= 1) {
    if (tid < off) { rs[tid] += rs[tid + off]; rq[tid] += rq[tid + off]; }
    __syncthreads();
  }
  if (tid == 0) {
    float mean = rs[0] * (1.f / 51200.f);
    float var = rq[0] * (1.f / 51200.f) - mean * mean;
    stats[b * 2] = mean;
    stats[b * 2 + 1] = rsqrtf(var + 1e-5f);
  }
}

__launch_bounds__(256)
__global__ void ln_apply(float* __restrict__ y, const float* __restrict__ stats) {
  const long i4 = (long)blockIdx.x * 256 + threadIdx.x;  // < 3276800
  const int b = (int)(i4 / 12800);
  float mu = stats[b * 2], rstd = stats[b * 2 + 1];
  f32x4 v = *(const f32x4*)&y[i4 * 4];
#pragma unroll
  for (int j = 0; j < 4; ++j) v[j] = (v[j] - mu) * rstd;
  *(f32x4*)&y[i4 * 4] = v;
}

extern "C" void kernel_launch(void* const* d_in, const int* in_sizes, int n_in,
                              void* d_out, int out_size, void* d_ws, size_t ws_size,
                              hipStream_t stream) {
  const float* x    = (const float*)d_in[0];
  const float* W_w  = (const float*)d_in[1];
  const float* W_b  = (const float*)d_in[2];
  const float* WK_w = (const float*)d_in[3];
  const float* WK_b = (const float*)d_in[4];
  const float* WQ_w = (const float*)d_in[5];
  const float* WQ_b = (const float*)d_in[6];
  const float* WV_w = (const float*)d_in[7];
  const float* WV_b = (const float*)d_in[8];
  const float* W2_w = (const float*)d_in[9];
  const float* W2_b = (const float*)d_in[10];
  float* out = (float*)d_out;

  // ---- workspace-adaptive batch chunking ----
  // fixed: xb 26,214,400 + WKQVt 25,165,824 + W1t 2,097,152 + W2t 2,097,152
  //        + bias 24,576 + stats + slack
  const size_t FIXED = 26214400ull + 25165824ull + 2097152ull + 2097152ull + 131072ull;
  // per-batch: h 409,600 + KQV 1,228,800 + sc 65,536 + P 32,768 + Vt 524,288 = 2,260,992
  const size_t PERB = 2260992ull;
  int CH = 256;
  if (ws_size == 0) CH = 32;
  else { while (CH > 4 && FIXED + (size_t)CH * PERB + 4096 > ws_size) CH >>= 1; }
  const int NCH = 256 / CH;
  const int CHR = CH * 100;                    // rows per chunk
  const int GX = (CHR + 127) / 128;            // M-tiles per chunk

  char* p = (char*)d_ws;
  auto carve = [&](size_t bytes) { char* r = p; p += (bytes + 255) & ~(size_t)255; return r; };
  u16* xb     = (u16*)carve(26214400);                // x bf16 [25600][512]
  u16* W1t    = (u16*)carve(2097152);                 // [2048][512]
  u16* WKQVt  = (u16*)carve(25165824);                // [6144][2048]  (K|Q|V)
  u16* W2t    = (u16*)carve(2097152);                 // [512][2048]
  float* bkqv = (float*)carve(24576);                 // [6144]
  float* stats = (float*)carve(2048);
  u16* h    = (u16*)carve((size_t)CH * 409600);       // h bf16 [CHR][2048]; reused as o
  u16* KQV  = (u16*)carve((size_t)CH * 1228800);      // [CHR][6144]  K|Q|V strided views
  float* sc = (float*)carve((size_t)CH * 65536);      // scores f32 [CH][128][128]
  u16* P    = (u16*)carve((size_t)CH * 32768);        // P bf16 [CH][128][128]
  u16* Vt   = (u16*)carve((size_t)CH * 524288);       // [CH][2048][128]

  cast_f32_to_bf16<<<2048, 256, 0, stream>>>(x, xb, 3276800);
  transpose_cast_w<<<dim3(32, 8),  256, 0, stream>>>(W_w,  W1t, 512, 2048);
  transpose_cast_w<<<dim3(32, 32), 256, 0, stream>>>(WK_w, WKQVt,            2048, 2048);
  transpose_cast_w<<<dim3(32, 32), 256, 0, stream>>>(WQ_w, WKQVt + 2048 * 2048, 2048, 2048);
  transpose_cast_w<<<dim3(32, 32), 256, 0, stream>>>(WV_w, WKQVt + 4096 * 2048, 2048, 2048);
  transpose_cast_w<<<dim3(8, 32),  256, 0, stream>>>(W2_w, W2t, 2048, 512);
  concat_bias<<<24, 256, 0, stream>>>(WK_b, WQ_b, WV_b, bkqv);

  for (int c = 0; c < NCH; ++c) {
    const u16* xc = xb + (size_t)c * CHR * 512;
    const float* xf = x + (size_t)c * CHR * 512;
    float* outc = out + (size_t)c * CHR * 512;

    // h = relu(xc @ W + b)   M=CHR N=2048 K=512
    gemm_bt<0><<<dim3(GX, 16, 1), 256, 0, stream>>>(xc, 512, 0, CHR - 1, W1t, 512, 0, 2047,
                                                    h, 2048, 0, CHR, W_b, nullptr, 512, 1.f);
    // KQV = h @ [WK|WQ|WV] + b   M=CHR N=6144 K=2048  (one fused GEMM)
    gemm_bt<1><<<dim3(GX, 48, 1), 256, 0, stream>>>(h, 2048, 0, CHR - 1, WKQVt, 2048, 0, 6143,
                                                    KQV, 6144, 0, CHR, bkqv, nullptr, 2048, 1.f);
    // scores[b] = Q[b] @ K[b]^T / sqrt(512)   batched over CH (strided views into KQV)
    gemm_bt<2><<<dim3(1, 1, CH), 256, 0, stream>>>(KQV + 2048, 6144, 100, CHR - 1,
                                                   KQV,        6144, 100, CHR - 1,
                                                   sc, 128, 128, 1 << 30, nullptr, nullptr,
                                                   2048, 0.044194173824159216f);
    softmax_rows<<<CH * 32, 256, 0, stream>>>(sc, P);
    transpose_v64<<<dim3(32, 2, CH), 256, 0, stream>>>(KQV + 4096, Vt, 6144);
    // o[b] = P[b] @ Vt[b]^T   batched, N=2048, K=128 (o overwrites h)
    gemm_bt<3><<<dim3(1, 16, CH), 256, 0, stream>>>(P, 128, 128, CH * 128 - 1, Vt, 128, 2048,
                                                    CH * 2048 - 1, h, 2048, 100, 100,
                                                    nullptr, nullptr, 128, 1.f);
    // y = o @ W2 + b2 + x   M=CHR N=512 K=2048  (f32 out)
    gemm_bt<4><<<dim3(GX, 4, 1), 256, 0, stream>>>(h, 2048, 0, CHR - 1, W2t, 2048, 0, 511,
                                                   outc, 512, 0, CHR, W2_b, xf, 2048, 1.f);
  }

  ln_stats<<<256, 256, 0, stream>>>(out, stats);
  ln_apply<<<12800, 256, 0, stream>>>(out, stats);
}

// Round 4
// 1736.203 us; speedup vs baseline: 1.2489x; 1.1172x over previous
//
#include <hip/hip_runtime.h>
#include <hip/hip_bf16.h>

typedef unsigned int u32;
typedef unsigned short u16;
typedef __attribute__((ext_vector_type(4))) float f32x4;
typedef __attribute__((ext_vector_type(8))) short s16x8;
typedef __attribute__((ext_vector_type(4))) u16 u16x4;
typedef __attribute__((ext_vector_type(8))) u16 u16x8;

#define DEVFN __device__ __forceinline__

DEVFN u16 f2bf(float f) {
  u32 x = __builtin_bit_cast(u32, f);
  u32 r = x + 0x7fffu + ((x >> 16) & 1u);   // round-to-nearest-even
  return (u16)(r >> 16);
}

DEVFN void gload_lds16(const u16* g, u16* l) {
  __builtin_amdgcn_global_load_lds((const __attribute__((address_space(1))) u32*)g,
                                   (__attribute__((address_space(3))) u32*)l, 16, 0, 0);
}

// ===========================================================================
// 256x256-tile 8-wave phase-pipelined bf16 GEMM (KQV):  C = A[M,K] @ Bt[N,K]^T + bias
// BK=64 split into two K-32 half-slots; 4 rotating LDS slots per operand.
// Per phase: 12 ds_read_b128 + 4 global_load_lds + counted vmcnt(8) + 32 MFMA.
// LDS rows are 64B => fragment ds_read_b128 is bank-balanced (no swizzle needed).
// ===========================================================================
#define KQV_PHASE(Q, VMWAIT, DOSTAGE)                                          \
  {                                                                            \
    const int sl_ = (Q) & 3;                                                   \
    const u16* As_ = smem + sl_ * 8192;                                        \
    const u16* Bs_ = smem + 32768 + sl_ * 8192;                                \
    s16x8 fa_[8], fb_[4];                                                      \
    _Pragma("unroll") for (int mf = 0; mf < 8; ++mf)                           \
        fa_[mf] = *(const s16x8*)(As_ + rA[mf]);                               \
    _Pragma("unroll") for (int nf = 0; nf < 4; ++nf)                           \
        fb_[nf] = *(const s16x8*)(Bs_ + rB[nf]);                               \
    if (DOSTAGE) {                                                             \
      const int g_ = (Q) + 3;                                                  \
      const int gs_ = g_ & 3;                                                  \
      const int k0_ = (g_ >> 1) * 64 + (g_ & 1) * 32;                          \
      gload_lds16(aS0 + k0_, smemw + gs_ * 8192 + ldst);                       \
      gload_lds16(aS1 + k0_, smemw + gs_ * 8192 + 4096 + ldst);                \
      gload_lds16(bS0 + k0_, smemw + 32768 + gs_ * 8192 + ldst);               \
      gload_lds16(bS1 + k0_, smemw + 32768 + gs_ * 8192 + 4096 + ldst);        \
    }                                                                          \
    __builtin_amdgcn_sched_barrier(0);                                         \
    VMWAIT;                                                                    \
    __builtin_amdgcn_s_barrier();                                              \
    __builtin_amdgcn_s_setprio(1);                                             \
    _Pragma("unroll") for (int mf = 0; mf < 8; ++mf)                           \
      _Pragma("unroll") for (int nf = 0; nf < 4; ++nf)                         \
        acc[mf][nf] = __builtin_amdgcn_mfma_f32_16x16x32_bf16(                 \
            fa_[mf], fb_[nf], acc[mf][nf], 0, 0, 0);                           \
    __builtin_amdgcn_s_setprio(0);                                             \
    __builtin_amdgcn_sched_barrier(0);                                         \
    __builtin_amdgcn_s_barrier();                                              \
    __builtin_amdgcn_sched_barrier(0);                                         \
  }

#define WAITV8 asm volatile("s_waitcnt vmcnt(8)" ::: "memory")
#define WAITV4 asm volatile("s_waitcnt vmcnt(4)" ::: "memory")
#define WAITV0 asm volatile("s_waitcnt vmcnt(0)" ::: "memory")
#define WAITNONE ((void)0)

__launch_bounds__(512)
__global__ void gemm256_kqv(const u16* __restrict__ Ag, int lda,
                            const u16* __restrict__ Bg, int ldb,
                            u16* __restrict__ C, int ldc,
                            const float* __restrict__ bias,
                            int M, int K, int ntiles) {
  extern __shared__ u16 smem_dyn[];
  const u16* smem = smem_dyn;
  u16* smemw = smem_dyn;

  const int tid = threadIdx.x;
  const int lane = tid & 63, wave = tid >> 6;
  const int wm = wave >> 2, wn = wave & 3;          // 2 (M) x 4 (N) waves
  const int l15 = lane & 15, l4 = lane >> 4;

  // bijective XCD-aware swizzle (m204)
  const int nwg = gridDim.x;
  const int q8 = nwg >> 3, r8 = nwg & 7;
  const int xcd = blockIdx.x & 7, io = blockIdx.x >> 3;
  const int wg = (xcd < r8) ? (xcd * (q8 + 1) + io)
                            : (r8 * (q8 + 1) + (xcd - r8) * q8 + io);
  const int m0 = (wg / ntiles) * 256, n0 = (wg % ntiles) * 256;

  // fragment read offsets (u16 units; slot row stride = 32 u16 = 64B)
  int rA[8], rB[4];
#pragma unroll
  for (int mf = 0; mf < 8; ++mf) rA[mf] = (wm * 128 + mf * 16 + l15) * 32 + l4 * 8;
#pragma unroll
  for (int nf = 0; nf < 4; ++nf) rB[nf] = (wn * 64 + nf * 16 + l15) * 32 + l4 * 8;

  // staging sources: thread -> (row = tid>>2 [+128 for instr 1], 16B chunk = tid&3)
  const int srow = tid >> 2;
  const int scol = (tid & 3) * 8;
  long ar0 = m0 + srow;        if (ar0 > M - 1) ar0 = M - 1;
  long ar1 = m0 + 128 + srow;  if (ar1 > M - 1) ar1 = M - 1;
  const u16* aS0 = Ag + ar0 * (long)lda + scol;
  const u16* aS1 = Ag + ar1 * (long)lda + scol;
  const u16* bS0 = Bg + (long)(n0 + srow) * ldb + scol;
  const u16* bS1 = Bg + (long)(n0 + 128 + srow) * ldb + scol;
  const int ldst = tid * 8;                       // u16 offset (16B per thread)

  f32x4 acc[8][4];
#pragma unroll
  for (int i = 0; i < 8; ++i)
#pragma unroll
    for (int j = 0; j < 4; ++j) acc[i][j] = (f32x4){0.f, 0.f, 0.f, 0.f};

  const int NT = K >> 6;                          // K-tiles (>=3 required)

  // prologue: stage groups 0,1,2 (slots 0,1,2), wait oldest (group 0) landed
  {
#pragma unroll
    for (int g_ = 0; g_ < 3; ++g_) {
      const int k0_ = (g_ >> 1) * 64 + (g_ & 1) * 32;
      gload_lds16(aS0 + k0_, smemw + g_ * 8192 + ldst);
      gload_lds16(aS1 + k0_, smemw + g_ * 8192 + 4096 + ldst);
      gload_lds16(bS0 + k0_, smemw + 32768 + g_ * 8192 + ldst);
      gload_lds16(bS1 + k0_, smemw + 32768 + g_ * 8192 + 4096 + ldst);
    }
    __builtin_amdgcn_sched_barrier(0);
    WAITV8;
    __builtin_amdgcn_s_barrier();
    __builtin_amdgcn_sched_barrier(0);
  }

  for (int t = 0; t < NT - 2; ++t) {
    KQV_PHASE(2 * t,     WAITV8, true);
    KQV_PHASE(2 * t + 1, WAITV8, true);
  }
  KQV_PHASE(2 * NT - 4, WAITV8,   true);    // stages last group (2NT-1)
  KQV_PHASE(2 * NT - 3, WAITV4,   false);
  KQV_PHASE(2 * NT - 2, WAITV0,   false);
  KQV_PHASE(2 * NT - 1, WAITNONE, false);

  // epilogue: C/D map col=lane&15, row=4*(lane>>4)+reg
#pragma unroll
  for (int mf = 0; mf < 8; ++mf) {
#pragma unroll
    for (int nf = 0; nf < 4; ++nf) {
      const int n = n0 + wn * 64 + nf * 16 + l15;
      const float bv = bias[n];
#pragma unroll
      for (int r = 0; r < 4; ++r) {
        const int s = wm * 128 + mf * 16 + l4 * 4 + r;
        if (m0 + s >= M) continue;
        C[(long)(m0 + s) * ldc + n] = f2bf(acc[mf][nf][r] + bv);
      }
    }
  }
}

// ---------------------------------------------------------------------------
// Generic bf16 MFMA GEMM (m97 128x128 structure) for the remaining matmuls.
// MODE 0: bf16 C = relu(acc + bias[n])            (GEMM1 -> h)
// MODE 2: f32  C = acc * scale                    (QK^T -> scores, batched)
// MODE 3: bf16 C = acc                            (PV -> o, batched, row guard)
// MODE 4: f32  C = acc + bias[n] + resid[ci]      (GEMM2 -> y)
// ---------------------------------------------------------------------------
template<int MODE>
__launch_bounds__(256)
__global__ void gemm_bt(const u16* __restrict__ Ag, int lda, int aRPB, int aRowMax,
                        const u16* __restrict__ Bg, int ldb, int bRPB, int bRowMax,
                        void* __restrict__ Cptr, int ldc, int cRPB, int cRowGuard,
                        const float* __restrict__ bias, const float* __restrict__ resid,
                        int K, float scale) {
  __shared__ __align__(16) u16 As[128 * 64];
  __shared__ __align__(16) u16 Bs[128 * 64];
  const int tid = threadIdx.x;
  const int lane = tid & 63, wid = tid >> 6;
  const int l15 = lane & 15, l4 = lane >> 4;
  const int wr = wid >> 1, wc = wid & 1;
  const int m0 = blockIdx.x * 128, n0 = blockIdx.y * 128;
  const int b = blockIdx.z;

  const u16* aSrc[4];
  const u16* bSrc[4];
  u16* aDst[4];
  u16* bDst[4];
#pragma unroll
  for (int i = 0; i < 4; ++i) {
    int c = i * 256 + tid;
    int r = c >> 3, g = c & 7;
    long arow = (long)b * aRPB + m0 + r; if (arow > aRowMax) arow = aRowMax;
    aSrc[i] = Ag + arow * (long)lda + g * 8;
    aDst[i] = &As[c * 8];
    long brow = (long)b * bRPB + n0 + r; if (brow > bRowMax) brow = bRowMax;
    bSrc[i] = Bg + brow * (long)ldb + g * 8;
    bDst[i] = &Bs[c * 8];
  }

  f32x4 acc[4][4];
#pragma unroll
  for (int i = 0; i < 4; ++i)
#pragma unroll
    for (int j = 0; j < 4; ++j) acc[i][j] = (f32x4){0.f, 0.f, 0.f, 0.f};

  for (int kt = 0; kt < K; kt += 64) {
#pragma unroll
    for (int i = 0; i < 4; ++i) gload_lds16(aSrc[i] + kt, aDst[i]);
#pragma unroll
    for (int i = 0; i < 4; ++i) gload_lds16(bSrc[i] + kt, bDst[i]);
    __syncthreads();
#pragma unroll
    for (int kk = 0; kk < 2; ++kk) {
      s16x8 af[4], bfr[4];
#pragma unroll
      for (int mi = 0; mi < 4; ++mi) {
        int rr = wr * 64 + mi * 16 + l15;
        af[mi] = *(const s16x8*)&As[rr * 64 + kk * 32 + l4 * 8];
      }
#pragma unroll
      for (int ni = 0; ni < 4; ++ni) {
        int rr = wc * 64 + ni * 16 + l15;
        bfr[ni] = *(const s16x8*)&Bs[rr * 64 + kk * 32 + l4 * 8];
      }
#pragma unroll
      for (int mi = 0; mi < 4; ++mi)
#pragma unroll
        for (int ni = 0; ni < 4; ++ni)
          acc[mi][ni] = __builtin_amdgcn_mfma_f32_16x16x32_bf16(af[mi], bfr[ni], acc[mi][ni], 0, 0, 0);
    }
    __syncthreads();
  }

  const long cRow0 = (long)b * cRPB + m0;
#pragma unroll
  for (int mi = 0; mi < 4; ++mi) {
#pragma unroll
    for (int ni = 0; ni < 4; ++ni) {
      const int n = n0 + wc * 64 + ni * 16 + l15;
      float bv = 0.f;
      if (MODE == 0 || MODE == 4) bv = bias[n];
#pragma unroll
      for (int r = 0; r < 4; ++r) {
        const int s = wr * 64 + mi * 16 + l4 * 4 + r;
        if (m0 + s >= cRowGuard) continue;
        const long ci = (cRow0 + s) * (long)ldc + n;
        float v = acc[mi][ni][r];
        if (MODE == 0)      { v += bv; v = v > 0.f ? v : 0.f; ((u16*)Cptr)[ci] = f2bf(v); }
        else if (MODE == 2) { ((float*)Cptr)[ci] = v * scale; }
        else if (MODE == 3) { ((u16*)Cptr)[ci] = f2bf(v); }
        else                { ((float*)Cptr)[ci] = v + bv + resid[ci]; }
      }
    }
  }
}

// masked row softmax over scores[CH][128][128] -> P bf16 [CH][128][128]
__launch_bounds__(256)
__global__ void softmax_rows(const float* __restrict__ S, u16* __restrict__ P) {
  const int wid = threadIdx.x >> 6, lane = threadIdx.x & 63;
  const long rowg = (long)blockIdx.x * 4 + wid;
  const int i = (int)(rowg & 127);
  const float* srow = S + rowg * 128;
  u16* prow = P + rowg * 128;
  if (i >= 100) { prow[lane] = 0; prow[lane + 64] = 0; return; }
  const int jmax = (i + 1 < 99) ? i + 1 : 99;          // tril(k=1): j <= i+1, j < 100
  float s0 = srow[lane], s1 = srow[lane + 64];
  bool v0 = lane <= jmax, v1 = (lane + 64) <= jmax;
  float m = fmaxf(v0 ? s0 : -3e38f, v1 ? s1 : -3e38f);
#pragma unroll
  for (int off = 32; off; off >>= 1) m = fmaxf(m, __shfl_xor(m, off));
  float e0 = v0 ? __expf(s0 - m) : 0.f;
  float e1 = v1 ? __expf(s1 - m) : 0.f;
  float sum = e0 + e1;
#pragma unroll
  for (int off = 32; off; off >>= 1) sum += __shfl_xor(sum, off);
  float rs = 1.f / sum;
  prow[lane] = f2bf(e0 * rs);
  prow[lane + 64] = f2bf(e1 * rs);
}

// transpose-cast fp32 W[K][N] -> bf16 Wt[N][K]
__launch_bounds__(256)
__global__ void transpose_cast_w(const float* __restrict__ W, u16* __restrict__ Wt,
                                 int K, int N) {
  __shared__ __align__(16) float t[64][68];
  const int tid = threadIdx.x;
  const int n0 = blockIdx.x * 64, k0 = blockIdx.y * 64;
#pragma unroll
  for (int it = 0; it < 4; ++it) {
    int c = it * 256 + tid;
    int r = c >> 4, cc = (c & 15) * 4;
    f32x4 v = *(const f32x4*)&W[(long)(k0 + r) * N + n0 + cc];
    *(f32x4*)&t[r][cc] = v;
  }
  __syncthreads();
#pragma unroll
  for (int it = 0; it < 4; ++it) {
    int c = it * 256 + tid;
    int n = c >> 4, kk = (c & 15) * 4;
    u16x4 o;
#pragma unroll
    for (int j = 0; j < 4; ++j) o[j] = f2bf(t[kk + j][n]);
    *(u16x4*)&Wt[(long)(n0 + n) * K + k0 + kk] = o;
  }
}

__launch_bounds__(256)
__global__ void cast_f32_to_bf16(const float* __restrict__ in, u16* __restrict__ out, long n4) {
  for (long i = (long)blockIdx.x * 256 + threadIdx.x; i < n4; i += (long)gridDim.x * 256) {
    f32x4 v = *(const f32x4*)&in[i * 4];
    u16x4 o;
#pragma unroll
    for (int j = 0; j < 4; ++j) o[j] = f2bf(v[j]);
    *(u16x4*)&out[i * 4] = o;
  }
}

// concat 3x2048 f32 bias vectors -> one [6144]
__launch_bounds__(256)
__global__ void concat_bias(const float* __restrict__ a, const float* __restrict__ b,
                            const float* __restrict__ c, float* __restrict__ o) {
  int i = blockIdx.x * 256 + threadIdx.x;   // < 6144
  o[i] = i < 2048 ? a[i] : (i < 4096 ? b[i - 2048] : c[i - 4096]);
}

// V view [CH*100][vstride] bf16 -> Vt [CH][2048][128] bf16 (zero-padded s>=100)
__launch_bounds__(256)
__global__ void transpose_v64(const u16* __restrict__ V, u16* __restrict__ Vt, int vstride) {
  __shared__ __align__(16) u16 t[64][72];
  const int tid = threadIdx.x;
  const int h0 = blockIdx.x * 64, s0 = blockIdx.y * 64, b = blockIdx.z;
#pragma unroll
  for (int it = 0; it < 2; ++it) {
    int c = it * 256 + tid;
    int s = c >> 3, hh = (c & 7) * 8;
    u16x8 v = {0, 0, 0, 0, 0, 0, 0, 0};
    if (s0 + s < 100) v = *(const u16x8*)&V[((long)b * 100 + s0 + s) * vstride + h0 + hh];
    *(u16x8*)&t[s][hh] = v;
  }
  __syncthreads();
#pragma unroll
  for (int it = 0; it < 2; ++it) {
    int c = it * 256 + tid;
    int h = c >> 3, ss = (c & 7) * 8;
    u16x8 o;
#pragma unroll
    for (int j = 0; j < 8; ++j) o[j] = t[ss + j][h];
    *(u16x8*)&Vt[((long)b * 2048 + h0 + h) * 128 + s0 + ss] = o;
  }
}

__launch_bounds__(256)
__global__ void ln_stats(const float* __restrict__ y, float* __restrict__ stats) {
  __shared__ float rs[256], rq[256];
  const int b = blockIdx.x, tid = threadIdx.x;
  const float* yb = y + (long)b * 51200;
  float s = 0.f, q = 0.f;
  for (int i = tid; i < 51200; i += 256) { float v = yb[i]; s += v; q += v * v; }
  rs[tid] = s; rq[tid] = q;
  __syncthreads();
  for (int off = 128; off; off >>= 1) {
    if (tid < off) { rs[tid] += rs[tid + off]; rq[tid] += rq[tid + off]; }
    __syncthreads();
  }
  if (tid == 0) {
    float mean = rs[0] * (1.f / 51200.f);
    float var = rq[0] * (1.f / 51200.f) - mean * mean;
    stats[b * 2] = mean;
    stats[b * 2 + 1] = rsqrtf(var + 1e-5f);
  }
}

__launch_bounds__(256)
__global__ void ln_apply(float* __restrict__ y, const float* __restrict__ stats) {
  const long i4 = (long)blockIdx.x * 256 + threadIdx.x;  // < 3276800
  const int b = (int)(i4 / 12800);
  float mu = stats[b * 2], rstd = stats[b * 2 + 1];
  f32x4 v = *(const f32x4*)&y[i4 * 4];
#pragma unroll
  for (int j = 0; j < 4; ++j) v[j] = (v[j] - mu) * rstd;
  *(f32x4*)&y[i4 * 4] = v;
}

extern "C" void kernel_launch(void* const* d_in, const int* in_sizes, int n_in,
                              void* d_out, int out_size, void* d_ws, size_t ws_size,
                              hipStream_t stream) {
  const float* x    = (const float*)d_in[0];
  const float* W_w  = (const float*)d_in[1];
  const float* W_b  = (const float*)d_in[2];
  const float* WK_w = (const float*)d_in[3];
  const float* WK_b = (const float*)d_in[4];
  const float* WQ_w = (const float*)d_in[5];
  const float* WQ_b = (const float*)d_in[6];
  const float* WV_w = (const float*)d_in[7];
  const float* WV_b = (const float*)d_in[8];
  const float* W2_w = (const float*)d_in[9];
  const float* W2_b = (const float*)d_in[10];
  float* out = (float*)d_out;

  // ---- workspace-adaptive batch chunking ----
  const size_t FIXED = 26214400ull + 25165824ull + 2097152ull + 2097152ull + 131072ull;
  const size_t PERB = 2260992ull;
  int CH = 256;
  if (ws_size == 0) CH = 32;
  else { while (CH > 4 && FIXED + (size_t)CH * PERB + 4096 > ws_size) CH >>= 1; }
  const int NCH = 256 / CH;
  const int CHR = CH * 100;                    // rows per chunk
  const int GX = (CHR + 127) / 128;            // 128-tiles per chunk
  const int MT256 = (CHR + 255) / 256;         // 256-tiles per chunk

  char* p = (char*)d_ws;
  auto carve = [&](size_t bytes) { char* r = p; p += (bytes + 255) & ~(size_t)255; return r; };
  u16* xb     = (u16*)carve(26214400);                // x bf16 [25600][512]
  u16* W1t    = (u16*)carve(2097152);                 // [2048][512]
  u16* WKQVt  = (u16*)carve(25165824);                // [6144][2048]  (K|Q|V)
  u16* W2t    = (u16*)carve(2097152);                 // [512][2048]
  float* bkqv = (float*)carve(24576);                 // [6144]
  float* stats = (float*)carve(2048);
  u16* h    = (u16*)carve((size_t)CH * 409600);       // h bf16 [CHR][2048]; reused as o
  u16* KQV  = (u16*)carve((size_t)CH * 1228800);      // [CHR][6144]  K|Q|V strided views
  float* sc = (float*)carve((size_t)CH * 65536);      // scores f32 [CH][128][128]
  u16* P    = (u16*)carve((size_t)CH * 32768);        // P bf16 [CH][128][128]
  u16* Vt   = (u16*)carve((size_t)CH * 524288);       // [CH][2048][128]

  cast_f32_to_bf16<<<2048, 256, 0, stream>>>(x, xb, 3276800);
  transpose_cast_w<<<dim3(32, 8),  256, 0, stream>>>(W_w,  W1t, 512, 2048);
  transpose_cast_w<<<dim3(32, 32), 256, 0, stream>>>(WK_w, WKQVt,               2048, 2048);
  transpose_cast_w<<<dim3(32, 32), 256, 0, stream>>>(WQ_w, WKQVt + 2048 * 2048, 2048, 2048);
  transpose_cast_w<<<dim3(32, 32), 256, 0, stream>>>(WV_w, WKQVt + 4096 * 2048, 2048, 2048);
  transpose_cast_w<<<dim3(8, 32),  256, 0, stream>>>(W2_w, W2t, 2048, 512);
  concat_bias<<<24, 256, 0, stream>>>(WK_b, WQ_b, WV_b, bkqv);

  for (int c = 0; c < NCH; ++c) {
    const u16* xc = xb + (size_t)c * CHR * 512;
    const float* xf = x + (size_t)c * CHR * 512;
    float* outc = out + (size_t)c * CHR * 512;

    // h = relu(xc @ W + b)   M=CHR N=2048 K=512
    gemm_bt<0><<<dim3(GX, 16, 1), 256, 0, stream>>>(xc, 512, 0, CHR - 1, W1t, 512, 0, 2047,
                                                    h, 2048, 0, CHR, W_b, nullptr, 512, 1.f);
    // KQV = h @ [WK|WQ|WV] + b   M=CHR N=6144 K=2048  (256^2 phase-pipelined)
    gemm256_kqv<<<MT256 * 24, 512, 131072, stream>>>(h, 2048, WKQVt, 2048,
                                                     KQV, 6144, bkqv, CHR, 2048, 24);
    // scores[b] = Q[b] @ K[b]^T / sqrt(512)   batched over CH (strided views into KQV)
    gemm_bt<2><<<dim3(1, 1, CH), 256, 0, stream>>>(KQV + 2048, 6144, 100, CHR - 1,
                                                   KQV,        6144, 100, CHR - 1,
                                                   sc, 128, 128, 1 << 30, nullptr, nullptr,
                                                   2048, 0.044194173824159216f);
    softmax_rows<<<CH * 32, 256, 0, stream>>>(sc, P);
    transpose_v64<<<dim3(32, 2, CH), 256, 0, stream>>>(KQV + 4096, Vt, 6144);
    // o[b] = P[b] @ Vt[b]^T   batched, N=2048, K=128 (o overwrites h)
    gemm_bt<3><<<dim3(1, 16, CH), 256, 0, stream>>>(P, 128, 128, CH * 128 - 1, Vt, 128, 2048,
                                                    CH * 2048 - 1, h, 2048, 100, 100,
                                                    nullptr, nullptr, 128, 1.f);
    // y = o @ W2 + b2 + x   M=CHR N=512 K=2048  (f32 out)
    gemm_bt<4><<<dim3(GX, 4, 1), 256, 0, stream>>>(h, 2048, 0, CHR - 1, W2t, 2048, 0, 511,
                                                   outc, 512, 0, CHR, W2_b, xf, 2048, 1.f);
  }

  ln_stats<<<256, 256, 0, stream>>>(out, stats);
  ln_apply<<<12800, 256, 0, stream>>>(out, stats);
}

// Round 5
// 1625.487 us; speedup vs baseline: 1.3340x; 1.0681x over previous
//
#include <hip/hip_runtime.h>
#include <hip/hip_bf16.h>

typedef unsigned int u32;
typedef unsigned short u16;
typedef __attribute__((ext_vector_type(4))) float f32x4;
typedef __attribute__((ext_vector_type(8))) short s16x8;
typedef __attribute__((ext_vector_type(4))) u16 u16x4;
typedef __attribute__((ext_vector_type(8))) u16 u16x8;

#define DEVFN __device__ __forceinline__

DEVFN u16 f2bf(float f) {
  u32 x = __builtin_bit_cast(u32, f);
  u32 r = x + 0x7fffu + ((x >> 16) & 1u);   // round-to-nearest-even
  return (u16)(r >> 16);
}

DEVFN void gload_lds16(const u16* g, u16* l) {
  __builtin_amdgcn_global_load_lds((const __attribute__((address_space(1))) u32*)g,
                                   (__attribute__((address_space(3))) u32*)l, 16, 0, 0);
}

// ===========================================================================
// 256x256-tile 8-wave phase-pipelined bf16 GEMM (KQV):  C = A[M,K] @ Bt[N,K]^T + bias
// BK=64 as two K-32 half-slots; 4 rotating LDS slots/operand; stage-2-ahead;
// ONE barrier per phase; counted vmcnt(4); chunk-XOR LDS swizzle:
//   LDS (row, chunk') holds global chunk (chunk' ^ ((row>>1)&3))
// applied on the READ side (fragment offsets) and via pre-swizzled GLOBAL
// source column on the write side (global_load_lds dest stays linear).
// ===========================================================================
#define KQV_PHASE(Q, VMWAIT, DOSTAGE)                                          \
  {                                                                            \
    if (DOSTAGE) {                                                             \
      const int g_ = (Q) + 2;                                                  \
      const int gs_ = g_ & 3;                                                  \
      const int k0_ = (g_ >> 1) * 64 + (g_ & 1) * 32;                          \
      gload_lds16(aS0 + k0_, smemw + gs_ * 8192 + ldst);                       \
      gload_lds16(aS1 + k0_, smemw + gs_ * 8192 + 4096 + ldst);                \
      gload_lds16(bS0 + k0_, smemw + 32768 + gs_ * 8192 + ldst);               \
      gload_lds16(bS1 + k0_, smemw + 32768 + gs_ * 8192 + 4096 + ldst);        \
    }                                                                          \
    const int sl_ = (Q) & 3;                                                   \
    const u16* As_ = smem + sl_ * 8192;                                        \
    const u16* Bs_ = smem + 32768 + sl_ * 8192;                                \
    s16x8 fa_[8], fb_[4];                                                      \
    _Pragma("unroll") for (int mf = 0; mf < 8; ++mf)                           \
        fa_[mf] = *(const s16x8*)(As_ + rA[mf]);                               \
    _Pragma("unroll") for (int nf = 0; nf < 4; ++nf)                           \
        fb_[nf] = *(const s16x8*)(Bs_ + rB[nf]);                               \
    __builtin_amdgcn_sched_barrier(0);                                         \
    VMWAIT;                                                                    \
    __builtin_amdgcn_s_barrier();                                              \
    __builtin_amdgcn_s_setprio(1);                                             \
    _Pragma("unroll") for (int mf = 0; mf < 8; ++mf)                           \
      _Pragma("unroll") for (int nf = 0; nf < 4; ++nf)                         \
        acc[mf][nf] = __builtin_amdgcn_mfma_f32_16x16x32_bf16(                 \
            fa_[mf], fb_[nf], acc[mf][nf], 0, 0, 0);                           \
    __builtin_amdgcn_s_setprio(0);                                             \
    __builtin_amdgcn_sched_barrier(0);                                         \
  }

#define WAITV4 asm volatile("s_waitcnt vmcnt(4)" ::: "memory")
#define WAITV0 asm volatile("s_waitcnt vmcnt(0)" ::: "memory")
#define WAITNONE ((void)0)

__launch_bounds__(512)
__global__ void gemm256_kqv(const u16* __restrict__ Ag, int lda,
                            const u16* __restrict__ Bg, int ldb,
                            u16* __restrict__ C, int ldc,
                            const float* __restrict__ bias,
                            int M, int K, int ntiles) {
  extern __shared__ u16 smem_dyn[];
  const u16* smem = smem_dyn;
  u16* smemw = smem_dyn;

  const int tid = threadIdx.x;
  const int lane = tid & 63, wave = tid >> 6;
  const int wm = wave >> 2, wn = wave & 3;          // 2 (M) x 4 (N) waves
  const int l15 = lane & 15, l4 = lane >> 4;

  // bijective XCD-aware swizzle (m204)
  const int nwg = gridDim.x;
  const int q8 = nwg >> 3, r8 = nwg & 7;
  const int xcd = blockIdx.x & 7, io = blockIdx.x >> 3;
  const int wg = (xcd < r8) ? (xcd * (q8 + 1) + io)
                            : (r8 * (q8 + 1) + (xcd - r8) * q8 + io);
  const int m0 = (wg / ntiles) * 256, n0 = (wg % ntiles) * 256;

  // fragment read offsets (u16 units; slot row stride = 32 u16 = 64B),
  // chunk-XOR swizzled: chunk' = l4 ^ ((row>>1)&3)
  int rA[8], rB[4];
#pragma unroll
  for (int mf = 0; mf < 8; ++mf) {
    const int r = wm * 128 + mf * 16 + l15;
    rA[mf] = r * 32 + ((l4 ^ ((r >> 1) & 3)) * 8);
  }
#pragma unroll
  for (int nf = 0; nf < 4; ++nf) {
    const int r = wn * 64 + nf * 16 + l15;
    rB[nf] = r * 32 + ((l4 ^ ((r >> 1) & 3)) * 8);
  }

  // staging: thread -> LDS (row = tid>>2, chunk = tid&3) [linear dest];
  // global source chunk pre-swizzled so LDS(row,c') = global chunk c'^((row>>1)&3)
  const int srow = tid >> 2;
  const int scol = (((tid & 3) ^ ((tid >> 3) & 3))) * 8;
  long ar0 = m0 + srow;        if (ar0 > M - 1) ar0 = M - 1;
  long ar1 = m0 + 128 + srow;  if (ar1 > M - 1) ar1 = M - 1;
  const u16* aS0 = Ag + ar0 * (long)lda + scol;
  const u16* aS1 = Ag + ar1 * (long)lda + scol;
  const u16* bS0 = Bg + (long)(n0 + srow) * ldb + scol;
  const u16* bS1 = Bg + (long)(n0 + 128 + srow) * ldb + scol;
  const int ldst = tid * 8;                       // u16 offset (16B per thread)

  f32x4 acc[8][4];
#pragma unroll
  for (int i = 0; i < 8; ++i)
#pragma unroll
    for (int j = 0; j < 4; ++j) acc[i][j] = (f32x4){0.f, 0.f, 0.f, 0.f};

  const int NT = K >> 6;                          // K-tiles (needs NT>=2)

  // prologue: stage groups 0,1 (slots 0,1); wait group 0 landed
  {
#pragma unroll
    for (int g_ = 0; g_ < 2; ++g_) {
      const int k0_ = (g_ >> 1) * 64 + (g_ & 1) * 32;
      gload_lds16(aS0 + k0_, smemw + g_ * 8192 + ldst);
      gload_lds16(aS1 + k0_, smemw + g_ * 8192 + 4096 + ldst);
      gload_lds16(bS0 + k0_, smemw + 32768 + g_ * 8192 + ldst);
      gload_lds16(bS1 + k0_, smemw + 32768 + g_ * 8192 + 4096 + ldst);
    }
    __builtin_amdgcn_sched_barrier(0);
    WAITV4;
    __builtin_amdgcn_s_barrier();
    __builtin_amdgcn_sched_barrier(0);
  }

  for (int t = 0; t < NT - 1; ++t) {
    KQV_PHASE(2 * t,     WAITV4, true);
    KQV_PHASE(2 * t + 1, WAITV4, true);
  }
  KQV_PHASE(2 * NT - 2, WAITV0,   false);
  KQV_PHASE(2 * NT - 1, WAITNONE, false);

  // epilogue: C/D map col=lane&15, row=4*(lane>>4)+reg
#pragma unroll
  for (int mf = 0; mf < 8; ++mf) {
#pragma unroll
    for (int nf = 0; nf < 4; ++nf) {
      const int n = n0 + wn * 64 + nf * 16 + l15;
      const float bv = bias[n];
#pragma unroll
      for (int r = 0; r < 4; ++r) {
        const int s = wm * 128 + mf * 16 + l4 * 4 + r;
        if (m0 + s >= M) continue;
        C[(long)(m0 + s) * ldc + n] = f2bf(acc[mf][nf][r] + bv);
      }
    }
  }
}

// ---------------------------------------------------------------------------
// Generic bf16 MFMA GEMM (m97 128x128 structure) for the remaining matmuls.
// MODE 0: bf16 C = relu(acc + bias[n])            (GEMM1 -> h)
// MODE 2: f32  C = acc * scale                    (QK^T -> scores, batched)
// MODE 3: bf16 C = acc                            (PV -> o, batched, row guard)
// MODE 4: f32  C = acc + bias[n] + resid[ci]      (GEMM2 -> y)
// ---------------------------------------------------------------------------
template<int MODE>
__launch_bounds__(256)
__global__ void gemm_bt(const u16* __restrict__ Ag, int lda, int aRPB, int aRowMax,
                        const u16* __restrict__ Bg, int ldb, int bRPB, int bRowMax,
                        void* __restrict__ Cptr, int ldc, int cRPB, int cRowGuard,
                        const float* __restrict__ bias, const float* __restrict__ resid,
                        int K, float scale) {
  __shared__ __align__(16) u16 As[128 * 64];
  __shared__ __align__(16) u16 Bs[128 * 64];
  const int tid = threadIdx.x;
  const int lane = tid & 63, wid = tid >> 6;
  const int l15 = lane & 15, l4 = lane >> 4;
  const int wr = wid >> 1, wc = wid & 1;
  const int m0 = blockIdx.x * 128, n0 = blockIdx.y * 128;
  const int b = blockIdx.z;

  const u16* aSrc[4];
  const u16* bSrc[4];
  u16* aDst[4];
  u16* bDst[4];
#pragma unroll
  for (int i = 0; i < 4; ++i) {
    int c = i * 256 + tid;
    int r = c >> 3, g = c & 7;
    long arow = (long)b * aRPB + m0 + r; if (arow > aRowMax) arow = aRowMax;
    aSrc[i] = Ag + arow * (long)lda + g * 8;
    aDst[i] = &As[c * 8];
    long brow = (long)b * bRPB + n0 + r; if (brow > bRowMax) brow = bRowMax;
    bSrc[i] = Bg + brow * (long)ldb + g * 8;
    bDst[i] = &Bs[c * 8];
  }

  f32x4 acc[4][4];
#pragma unroll
  for (int i = 0; i < 4; ++i)
#pragma unroll
    for (int j = 0; j < 4; ++j) acc[i][j] = (f32x4){0.f, 0.f, 0.f, 0.f};

  for (int kt = 0; kt < K; kt += 64) {
#pragma unroll
    for (int i = 0; i < 4; ++i) gload_lds16(aSrc[i] + kt, aDst[i]);
#pragma unroll
    for (int i = 0; i < 4; ++i) gload_lds16(bSrc[i] + kt, bDst[i]);
    __syncthreads();
#pragma unroll
    for (int kk = 0; kk < 2; ++kk) {
      s16x8 af[4], bfr[4];
#pragma unroll
      for (int mi = 0; mi < 4; ++mi) {
        int rr = wr * 64 + mi * 16 + l15;
        af[mi] = *(const s16x8*)&As[rr * 64 + kk * 32 + l4 * 8];
      }
#pragma unroll
      for (int ni = 0; ni < 4; ++ni) {
        int rr = wc * 64 + ni * 16 + l15;
        bfr[ni] = *(const s16x8*)&Bs[rr * 64 + kk * 32 + l4 * 8];
      }
#pragma unroll
      for (int mi = 0; mi < 4; ++mi)
#pragma unroll
        for (int ni = 0; ni < 4; ++ni)
          acc[mi][ni] = __builtin_amdgcn_mfma_f32_16x16x32_bf16(af[mi], bfr[ni], acc[mi][ni], 0, 0, 0);
    }
    __syncthreads();
  }

  const long cRow0 = (long)b * cRPB + m0;
#pragma unroll
  for (int mi = 0; mi < 4; ++mi) {
#pragma unroll
    for (int ni = 0; ni < 4; ++ni) {
      const int n = n0 + wc * 64 + ni * 16 + l15;
      float bv = 0.f;
      if (MODE == 0 || MODE == 4) bv = bias[n];
#pragma unroll
      for (int r = 0; r < 4; ++r) {
        const int s = wr * 64 + mi * 16 + l4 * 4 + r;
        if (m0 + s >= cRowGuard) continue;
        const long ci = (cRow0 + s) * (long)ldc + n;
        float v = acc[mi][ni][r];
        if (MODE == 0)      { v += bv; v = v > 0.f ? v : 0.f; ((u16*)Cptr)[ci] = f2bf(v); }
        else if (MODE == 2) { ((float*)Cptr)[ci] = v * scale; }
        else if (MODE == 3) { ((u16*)Cptr)[ci] = f2bf(v); }
        else                { ((float*)Cptr)[ci] = v + bv + resid[ci]; }
      }
    }
  }
}

// masked row softmax over scores[CH][128][128] -> P bf16 [CH][128][128]
__launch_bounds__(256)
__global__ void softmax_rows(const float* __restrict__ S, u16* __restrict__ P) {
  const int wid = threadIdx.x >> 6, lane = threadIdx.x & 63;
  const long rowg = (long)blockIdx.x * 4 + wid;
  const int i = (int)(rowg & 127);
  const float* srow = S + rowg * 128;
  u16* prow = P + rowg * 128;
  if (i >= 100) { prow[lane] = 0; prow[lane + 64] = 0; return; }
  const int jmax = (i + 1 < 99) ? i + 1 : 99;          // tril(k=1): j <= i+1, j < 100
  float s0 = srow[lane], s1 = srow[lane + 64];
  bool v0 = lane <= jmax, v1 = (lane + 64) <= jmax;
  float m = fmaxf(v0 ? s0 : -3e38f, v1 ? s1 : -3e38f);
#pragma unroll
  for (int off = 32; off; off >>= 1) m = fmaxf(m, __shfl_xor(m, off));
  float e0 = v0 ? __expf(s0 - m) : 0.f;
  float e1 = v1 ? __expf(s1 - m) : 0.f;
  float sum = e0 + e1;
#pragma unroll
  for (int off = 32; off; off >>= 1) sum += __shfl_xor(sum, off);
  float rs = 1.f / sum;
  prow[lane] = f2bf(e0 * rs);
  prow[lane + 64] = f2bf(e1 * rs);
}

// transpose-cast fp32 W[K][N] -> bf16 Wt[N][K]
__launch_bounds__(256)
__global__ void transpose_cast_w(const float* __restrict__ W, u16* __restrict__ Wt,
                                 int K, int N) {
  __shared__ __align__(16) float t[64][68];
  const int tid = threadIdx.x;
  const int n0 = blockIdx.x * 64, k0 = blockIdx.y * 64;
#pragma unroll
  for (int it = 0; it < 4; ++it) {
    int c = it * 256 + tid;
    int r = c >> 4, cc = (c & 15) * 4;
    f32x4 v = *(const f32x4*)&W[(long)(k0 + r) * N + n0 + cc];
    *(f32x4*)&t[r][cc] = v;
  }
  __syncthreads();
#pragma unroll
  for (int it = 0; it < 4; ++it) {
    int c = it * 256 + tid;
    int n = c >> 4, kk = (c & 15) * 4;
    u16x4 o;
#pragma unroll
    for (int j = 0; j < 4; ++j) o[j] = f2bf(t[kk + j][n]);
    *(u16x4*)&Wt[(long)(n0 + n) * K + k0 + kk] = o;
  }
}

__launch_bounds__(256)
__global__ void cast_f32_to_bf16(const float* __restrict__ in, u16* __restrict__ out, long n4) {
  for (long i = (long)blockIdx.x * 256 + threadIdx.x; i < n4; i += (long)gridDim.x * 256) {
    f32x4 v = *(const f32x4*)&in[i * 4];
    u16x4 o;
#pragma unroll
    for (int j = 0; j < 4; ++j) o[j] = f2bf(v[j]);
    *(u16x4*)&out[i * 4] = o;
  }
}

// concat 3x2048 f32 bias vectors -> one [6144]
__launch_bounds__(256)
__global__ void concat_bias(const float* __restrict__ a, const float* __restrict__ b,
                            const float* __restrict__ c, float* __restrict__ o) {
  int i = blockIdx.x * 256 + threadIdx.x;   // < 6144
  o[i] = i < 2048 ? a[i] : (i < 4096 ? b[i - 2048] : c[i - 4096]);
}

// V view [CH*100][vstride] bf16 -> Vt [CH][2048][128] bf16 (zero-padded s>=100)
__launch_bounds__(256)
__global__ void transpose_v64(const u16* __restrict__ V, u16* __restrict__ Vt, int vstride) {
  __shared__ __align__(16) u16 t[64][72];
  const int tid = threadIdx.x;
  const int h0 = blockIdx.x * 64, s0 = blockIdx.y * 64, b = blockIdx.z;
#pragma unroll
  for (int it = 0; it < 2; ++it) {
    int c = it * 256 + tid;
    int s = c >> 3, hh = (c & 7) * 8;
    u16x8 v = {0, 0, 0, 0, 0, 0, 0, 0};
    if (s0 + s < 100) v = *(const u16x8*)&V[((long)b * 100 + s0 + s) * vstride + h0 + hh];
    *(u16x8*)&t[s][hh] = v;
  }
  __syncthreads();
#pragma unroll
  for (int it = 0; it < 2; ++it) {
    int c = it * 256 + tid;
    int h = c >> 3, ss = (c & 7) * 8;
    u16x8 o;
#pragma unroll
    for (int j = 0; j < 8; ++j) o[j] = t[ss + j][h];
    *(u16x8*)&Vt[((long)b * 2048 + h0 + h) * 128 + s0 + ss] = o;
  }
}

__launch_bounds__(256)
__global__ void ln_stats(const float* __restrict__ y, float* __restrict__ stats) {
  __shared__ float rs[256], rq[256];
  const int b = blockIdx.x, tid = threadIdx.x;
  const float* yb = y + (long)b * 51200;
  float s = 0.f, q = 0.f;
  for (int i = tid; i < 51200; i += 256) { float v = yb[i]; s += v; q += v * v; }
  rs[tid] = s; rq[tid] = q;
  __syncthreads();
  for (int off = 128; off; off >>= 1) {
    if (tid < off) { rs[tid] += rs[tid + off]; rq[tid] += rq[tid + off]; }
    __syncthreads();
  }
  if (tid == 0) {
    float mean = rs[0] * (1.f / 51200.f);
    float var = rq[0] * (1.f / 51200.f) - mean * mean;
    stats[b * 2] = mean;
    stats[b * 2 + 1] = rsqrtf(var + 1e-5f);
  }
}

__launch_bounds__(256)
__global__ void ln_apply(float* __restrict__ y, const float* __restrict__ stats) {
  const long i4 = (long)blockIdx.x * 256 + threadIdx.x;  // < 3276800
  const int b = (int)(i4 / 12800);
  float mu = stats[b * 2], rstd = stats[b * 2 + 1];
  f32x4 v = *(const f32x4*)&y[i4 * 4];
#pragma unroll
  for (int j = 0; j < 4; ++j) v[j] = (v[j] - mu) * rstd;
  *(f32x4*)&y[i4 * 4] = v;
}

extern "C" void kernel_launch(void* const* d_in, const int* in_sizes, int n_in,
                              void* d_out, int out_size, void* d_ws, size_t ws_size,
                              hipStream_t stream) {
  const float* x    = (const float*)d_in[0];
  const float* W_w  = (const float*)d_in[1];
  const float* W_b  = (const float*)d_in[2];
  const float* WK_w = (const float*)d_in[3];
  const float* WK_b = (const float*)d_in[4];
  const float* WQ_w = (const float*)d_in[5];
  const float* WQ_b = (const float*)d_in[6];
  const float* WV_w = (const float*)d_in[7];
  const float* WV_b = (const float*)d_in[8];
  const float* W2_w = (const float*)d_in[9];
  const float* W2_b = (const float*)d_in[10];
  float* out = (float*)d_out;

  // ---- workspace-adaptive batch chunking ----
  const size_t FIXED = 26214400ull + 25165824ull + 2097152ull + 2097152ull + 131072ull;
  const size_t PERB = 2260992ull;
  int CH = 256;
  if (ws_size == 0) CH = 32;
  else { while (CH > 4 && FIXED + (size_t)CH * PERB + 4096 > ws_size) CH >>= 1; }
  const int NCH = 256 / CH;
  const int CHR = CH * 100;                    // rows per chunk
  const int GX = (CHR + 127) / 128;            // 128-tiles per chunk
  const int MT256 = (CHR + 255) / 256;         // 256-tiles per chunk

  char* p = (char*)d_ws;
  auto carve = [&](size_t bytes) { char* r = p; p += (bytes + 255) & ~(size_t)255; return r; };
  u16* xb     = (u16*)carve(26214400);                // x bf16 [25600][512]
  u16* W1t    = (u16*)carve(2097152);                 // [2048][512]
  u16* WKQVt  = (u16*)carve(25165824);                // [6144][2048]  (K|Q|V)
  u16* W2t    = (u16*)carve(2097152);                 // [512][2048]
  float* bkqv = (float*)carve(24576);                 // [6144]
  float* stats = (float*)carve(2048);
  u16* h    = (u16*)carve((size_t)CH * 409600);       // h bf16 [CHR][2048]; reused as o
  u16* KQV  = (u16*)carve((size_t)CH * 1228800);      // [CHR][6144]  K|Q|V strided views
  float* sc = (float*)carve((size_t)CH * 65536);      // scores f32 [CH][128][128]
  u16* P    = (u16*)carve((size_t)CH * 32768);        // P bf16 [CH][128][128]
  u16* Vt   = (u16*)carve((size_t)CH * 524288);       // [CH][2048][128]

  cast_f32_to_bf16<<<2048, 256, 0, stream>>>(x, xb, 3276800);
  transpose_cast_w<<<dim3(32, 8),  256, 0, stream>>>(W_w,  W1t, 512, 2048);
  transpose_cast_w<<<dim3(32, 32), 256, 0, stream>>>(WK_w, WKQVt,               2048, 2048);
  transpose_cast_w<<<dim3(32, 32), 256, 0, stream>>>(WQ_w, WKQVt + 2048 * 2048, 2048, 2048);
  transpose_cast_w<<<dim3(32, 32), 256, 0, stream>>>(WV_w, WKQVt + 4096 * 2048, 2048, 2048);
  transpose_cast_w<<<dim3(8, 32),  256, 0, stream>>>(W2_w, W2t, 2048, 512);
  concat_bias<<<24, 256, 0, stream>>>(WK_b, WQ_b, WV_b, bkqv);

  for (int c = 0; c < NCH; ++c) {
    const u16* xc = xb + (size_t)c * CHR * 512;
    const float* xf = x + (size_t)c * CHR * 512;
    float* outc = out + (size_t)c * CHR * 512;

    // h = relu(xc @ W + b)   M=CHR N=2048 K=512
    gemm_bt<0><<<dim3(GX, 16, 1), 256, 0, stream>>>(xc, 512, 0, CHR - 1, W1t, 512, 0, 2047,
                                                    h, 2048, 0, CHR, W_b, nullptr, 512, 1.f);
    // KQV = h @ [WK|WQ|WV] + b   M=CHR N=6144 K=2048  (256^2 phase-pipelined)
    gemm256_kqv<<<MT256 * 24, 512, 131072, stream>>>(h, 2048, WKQVt, 2048,
                                                     KQV, 6144, bkqv, CHR, 2048, 24);
    // scores[b] = Q[b] @ K[b]^T / sqrt(512)   batched over CH (strided views into KQV)
    gemm_bt<2><<<dim3(1, 1, CH), 256, 0, stream>>>(KQV + 2048, 6144, 100, CHR - 1,
                                                   KQV,        6144, 100, CHR - 1,
                                                   sc, 128, 128, 1 << 30, nullptr, nullptr,
                                                   2048, 0.044194173824159216f);
    softmax_rows<<<CH * 32, 256, 0, stream>>>(sc, P);
    transpose_v64<<<dim3(32, 2, CH), 256, 0, stream>>>(KQV + 4096, Vt, 6144);
    // o[b] = P[b] @ Vt[b]^T   batched, N=2048, K=128 (o overwrites h)
    gemm_bt<3><<<dim3(1, 16, CH), 256, 0, stream>>>(P, 128, 128, CH * 128 - 1, Vt, 128, 2048,
                                                    CH * 2048 - 1, h, 2048, 100, 100,
                                                    nullptr, nullptr, 128, 1.f);
    // y = o @ W2 + b2 + x   M=CHR N=512 K=2048  (f32 out)
    gemm_bt<4><<<dim3(GX, 4, 1), 256, 0, stream>>>(h, 2048, 0, CHR - 1, W2t, 2048, 0, 511,
                                                   outc, 512, 0, CHR, W2_b, xf, 2048, 1.f);
  }

  ln_stats<<<256, 256, 0, stream>>>(out, stats);
  ln_apply<<<12800, 256, 0, stream>>>(out, stats);
}

// Round 6
// 1619.236 us; speedup vs baseline: 1.3392x; 1.0039x over previous
//
#include <hip/hip_runtime.h>
#include <hip/hip_bf16.h>

typedef unsigned int u32;
typedef unsigned short u16;
typedef __attribute__((ext_vector_type(4))) float f32x4;
typedef __attribute__((ext_vector_type(8))) short s16x8;
typedef __attribute__((ext_vector_type(4))) u16 u16x4;
typedef __attribute__((ext_vector_type(8))) u16 u16x8;

#define DEVFN __device__ __forceinline__

DEVFN u16 f2bf(float f) {
  u32 x = __builtin_bit_cast(u32, f);
  u32 r = x + 0x7fffu + ((x >> 16) & 1u);   // round-to-nearest-even
  return (u16)(r >> 16);
}

DEVFN void gload_lds16(const u16* g, u16* l) {
  __builtin_amdgcn_global_load_lds((const __attribute__((address_space(1))) u32*)g,
                                   (__attribute__((address_space(3))) u32*)l, 16, 0, 0);
}

// ===========================================================================
// 256x256-tile 8-wave bf16 GEMM (KQV) with register-double-buffered fragments.
// BK=64 as two K-32 groups; group g -> LDS slot g&3 (4 rotating slots/operand).
// Phase q: [stage group q+2] [vmcnt(4)] [barrier] [ds_read frags(q+1) -> NXT]
//          [MFMA group q on CUR]   — reads overlap MFMA (independent regs).
// Safety: vmcnt BEFORE barrier => all waves' stage loads landed before any
// wave's post-barrier reads; slot re-write (q+5 staged at phase q+3) is >=1
// barrier after reads of that slot drained (MFMA q+1 consumes them).
// Chunk-XOR swizzle (verified round 5, conflicts=0): LDS chunk c holds global
// chunk c^((row>>1)&3); read offset reduces to lane-const (l4^((l15>>1)&3)).
// ===========================================================================
#define WAITV4 asm volatile("s_waitcnt vmcnt(4)" ::: "memory")
#define WAITV0 asm volatile("s_waitcnt vmcnt(0)" ::: "memory")
#define WAITNONE ((void)0)

#define KQV_PHASE(QMFMA, DOSTAGE, VM, DOREAD, CURA, CURB, NXTA, NXTB)          \
  {                                                                            \
    if (DOSTAGE) {                                                             \
      const int g_ = (QMFMA) + 2;                                              \
      const int sl_ = (g_ & 3) * 8192;                                         \
      const int k0_ = (g_ >> 1) * 64 + (g_ & 1) * 32;                          \
      gload_lds16(aS0 + k0_, smemw + sl_ + ldst);                              \
      gload_lds16(aS1 + k0_, smemw + sl_ + 4096 + ldst);                       \
      gload_lds16(bS0 + k0_, smemw + 32768 + sl_ + ldst);                      \
      gload_lds16(bS1 + k0_, smemw + 32768 + sl_ + 4096 + ldst);               \
    }                                                                          \
    VM;                                                                        \
    __builtin_amdgcn_s_barrier();                                              \
    if (DOREAD) {                                                              \
      const int rg_ = (QMFMA) + 1;                                             \
      const u16* As_ = smem + (rg_ & 3) * 8192 + baseA;                        \
      const u16* Bs_ = smem + 32768 + (rg_ & 3) * 8192 + baseB;                \
      _Pragma("unroll") for (int mf = 0; mf < 8; ++mf)                         \
          NXTA[mf] = *(const s16x8*)(As_ + mf * 512);                          \
      _Pragma("unroll") for (int nf = 0; nf < 4; ++nf)                         \
          NXTB[nf] = *(const s16x8*)(Bs_ + nf * 512);                          \
    }                                                                          \
    __builtin_amdgcn_s_setprio(1);                                             \
    _Pragma("unroll") for (int mf = 0; mf < 8; ++mf)                           \
      _Pragma("unroll") for (int nf = 0; nf < 4; ++nf)                         \
        acc[mf][nf] = __builtin_amdgcn_mfma_f32_16x16x32_bf16(                 \
            CURA[mf], CURB[nf], acc[mf][nf], 0, 0, 0);                         \
    __builtin_amdgcn_s_setprio(0);                                             \
  }

__launch_bounds__(512, 2)
__global__ void gemm256_kqv(const u16* __restrict__ Ag, int lda,
                            const u16* __restrict__ Bg, int ldb,
                            u16* __restrict__ C, int ldc,
                            const float* __restrict__ bias,
                            int M, int K, int ntiles) {
  extern __shared__ u16 smem_dyn[];
  const u16* smem = smem_dyn;
  u16* smemw = smem_dyn;

  const int tid = threadIdx.x;
  const int lane = tid & 63, wave = tid >> 6;
  const int wm = wave >> 2, wn = wave & 3;          // 2 (M) x 4 (N) waves
  const int l15 = lane & 15, l4 = lane >> 4;

  // bijective XCD-aware swizzle (m204)
  const int nwg = gridDim.x;
  const int q8 = nwg >> 3, r8 = nwg & 7;
  const int xcd = blockIdx.x & 7, io = blockIdx.x >> 3;
  const int wg = (xcd < r8) ? (xcd * (q8 + 1) + io)
                            : (r8 * (q8 + 1) + (xcd - r8) * q8 + io);
  const int m0 = (wg / ntiles) * 256, n0 = (wg % ntiles) * 256;

  // fragment bases (u16 units; slot row stride = 32 u16 = 64B).
  // swizzled chunk = l4 ^ ((row>>1)&3); row = base+mf*16+l15 with base,mf*16
  // both ≡0 mod 4 after >>1 => reduces to lane constant.
  const int chunkSwz = (l4 ^ ((l15 >> 1) & 3)) * 8;
  const int baseA = (wm * 128 + l15) * 32 + chunkSwz;
  const int baseB = (wn * 64 + l15) * 32 + chunkSwz;

  // staging: thread -> LDS (row = tid>>2, chunk = tid&3) [linear dest];
  // global source chunk pre-swizzled (verified: conflicts = 0)
  const int srow = tid >> 2;
  const int scol = (((tid & 3) ^ ((tid >> 3) & 3))) * 8;
  long ar0 = m0 + srow;        if (ar0 > M - 1) ar0 = M - 1;
  long ar1 = m0 + 128 + srow;  if (ar1 > M - 1) ar1 = M - 1;
  const u16* aS0 = Ag + ar0 * (long)lda + scol;
  const u16* aS1 = Ag + ar1 * (long)lda + scol;
  const u16* bS0 = Bg + (long)(n0 + srow) * ldb + scol;
  const u16* bS1 = Bg + (long)(n0 + 128 + srow) * ldb + scol;
  const int ldst = tid * 8;                       // u16 offset (16B per thread)

  f32x4 acc[8][4];
#pragma unroll
  for (int i = 0; i < 8; ++i)
#pragma unroll
    for (int j = 0; j < 4; ++j) acc[i][j] = (f32x4){0.f, 0.f, 0.f, 0.f};

  s16x8 fa0[8], fb0[4], fa1[8], fb1[4];           // double-buffered fragments

  const int NT = K >> 6;                          // K-tiles (needs NT>=2)

  // prologue: stage groups 0,1 (slots 0,1); wait group 0; read frags(0)->set0
  {
#pragma unroll
    for (int g_ = 0; g_ < 2; ++g_) {
      const int k0_ = g_ * 32;
      gload_lds16(aS0 + k0_, smemw + g_ * 8192 + ldst);
      gload_lds16(aS1 + k0_, smemw + g_ * 8192 + 4096 + ldst);
      gload_lds16(bS0 + k0_, smemw + 32768 + g_ * 8192 + ldst);
      gload_lds16(bS1 + k0_, smemw + 32768 + g_ * 8192 + 4096 + ldst);
    }
    WAITV4;
    __builtin_amdgcn_s_barrier();
    const u16* As_ = smem + baseA;
    const u16* Bs_ = smem + 32768 + baseB;
#pragma unroll
    for (int mf = 0; mf < 8; ++mf) fa0[mf] = *(const s16x8*)(As_ + mf * 512);
#pragma unroll
    for (int nf = 0; nf < 4; ++nf) fb0[nf] = *(const s16x8*)(Bs_ + nf * 512);
  }

  for (int t = 0; t < NT - 1; ++t) {
    KQV_PHASE(2 * t,     true, WAITV4, true, fa0, fb0, fa1, fb1);
    KQV_PHASE(2 * t + 1, true, WAITV4, true, fa1, fb1, fa0, fb0);
  }
  KQV_PHASE(2 * NT - 2, false, WAITV0,   true,  fa0, fb0, fa1, fb1);
  KQV_PHASE(2 * NT - 1, false, WAITNONE, false, fa1, fb1, fa0, fb0);

  // epilogue: C/D map col=lane&15, row=4*(lane>>4)+reg
#pragma unroll
  for (int mf = 0; mf < 8; ++mf) {
#pragma unroll
    for (int nf = 0; nf < 4; ++nf) {
      const int n = n0 + wn * 64 + nf * 16 + l15;
      const float bv = bias[n];
#pragma unroll
      for (int r = 0; r < 4; ++r) {
        const int s = wm * 128 + mf * 16 + l4 * 4 + r;
        if (m0 + s >= M) continue;
        C[(long)(m0 + s) * ldc + n] = f2bf(acc[mf][nf][r] + bv);
      }
    }
  }
}

// ---------------------------------------------------------------------------
// Generic bf16 MFMA GEMM (m97 128x128 structure) for the remaining matmuls.
// MODE 0: bf16 C = relu(acc + bias[n])            (GEMM1 -> h)
// MODE 2: f32  C = acc * scale                    (QK^T -> scores, batched)
// MODE 3: bf16 C = acc                            (PV -> o, batched, row guard)
// MODE 4: f32  C = acc + bias[n] + resid[ci]      (GEMM2 -> y)
// ---------------------------------------------------------------------------
template<int MODE>
__launch_bounds__(256)
__global__ void gemm_bt(const u16* __restrict__ Ag, int lda, int aRPB, int aRowMax,
                        const u16* __restrict__ Bg, int ldb, int bRPB, int bRowMax,
                        void* __restrict__ Cptr, int ldc, int cRPB, int cRowGuard,
                        const float* __restrict__ bias, const float* __restrict__ resid,
                        int K, float scale) {
  __shared__ __align__(16) u16 As[128 * 64];
  __shared__ __align__(16) u16 Bs[128 * 64];
  const int tid = threadIdx.x;
  const int lane = tid & 63, wid = tid >> 6;
  const int l15 = lane & 15, l4 = lane >> 4;
  const int wr = wid >> 1, wc = wid & 1;
  const int m0 = blockIdx.x * 128, n0 = blockIdx.y * 128;
  const int b = blockIdx.z;

  const u16* aSrc[4];
  const u16* bSrc[4];
  u16* aDst[4];
  u16* bDst[4];
#pragma unroll
  for (int i = 0; i < 4; ++i) {
    int c = i * 256 + tid;
    int r = c >> 3, g = c & 7;
    long arow = (long)b * aRPB + m0 + r; if (arow > aRowMax) arow = aRowMax;
    aSrc[i] = Ag + arow * (long)lda + g * 8;
    aDst[i] = &As[c * 8];
    long brow = (long)b * bRPB + n0 + r; if (brow > bRowMax) brow = bRowMax;
    bSrc[i] = Bg + brow * (long)ldb + g * 8;
    bDst[i] = &Bs[c * 8];
  }

  f32x4 acc[4][4];
#pragma unroll
  for (int i = 0; i < 4; ++i)
#pragma unroll
    for (int j = 0; j < 4; ++j) acc[i][j] = (f32x4){0.f, 0.f, 0.f, 0.f};

  for (int kt = 0; kt < K; kt += 64) {
#pragma unroll
    for (int i = 0; i < 4; ++i) gload_lds16(aSrc[i] + kt, aDst[i]);
#pragma unroll
    for (int i = 0; i < 4; ++i) gload_lds16(bSrc[i] + kt, bDst[i]);
    __syncthreads();
#pragma unroll
    for (int kk = 0; kk < 2; ++kk) {
      s16x8 af[4], bfr[4];
#pragma unroll
      for (int mi = 0; mi < 4; ++mi) {
        int rr = wr * 64 + mi * 16 + l15;
        af[mi] = *(const s16x8*)&As[rr * 64 + kk * 32 + l4 * 8];
      }
#pragma unroll
      for (int ni = 0; ni < 4; ++ni) {
        int rr = wc * 64 + ni * 16 + l15;
        bfr[ni] = *(const s16x8*)&Bs[rr * 64 + kk * 32 + l4 * 8];
      }
#pragma unroll
      for (int mi = 0; mi < 4; ++mi)
#pragma unroll
        for (int ni = 0; ni < 4; ++ni)
          acc[mi][ni] = __builtin_amdgcn_mfma_f32_16x16x32_bf16(af[mi], bfr[ni], acc[mi][ni], 0, 0, 0);
    }
    __syncthreads();
  }

  const long cRow0 = (long)b * cRPB + m0;
#pragma unroll
  for (int mi = 0; mi < 4; ++mi) {
#pragma unroll
    for (int ni = 0; ni < 4; ++ni) {
      const int n = n0 + wc * 64 + ni * 16 + l15;
      float bv = 0.f;
      if (MODE == 0 || MODE == 4) bv = bias[n];
#pragma unroll
      for (int r = 0; r < 4; ++r) {
        const int s = wr * 64 + mi * 16 + l4 * 4 + r;
        if (m0 + s >= cRowGuard) continue;
        const long ci = (cRow0 + s) * (long)ldc + n;
        float v = acc[mi][ni][r];
        if (MODE == 0)      { v += bv; v = v > 0.f ? v : 0.f; ((u16*)Cptr)[ci] = f2bf(v); }
        else if (MODE == 2) { ((float*)Cptr)[ci] = v * scale; }
        else if (MODE == 3) { ((u16*)Cptr)[ci] = f2bf(v); }
        else                { ((float*)Cptr)[ci] = v + bv + resid[ci]; }
      }
    }
  }
}

// masked row softmax over scores[CH][128][128] -> P bf16 [CH][128][128]
__launch_bounds__(256)
__global__ void softmax_rows(const float* __restrict__ S, u16* __restrict__ P) {
  const int wid = threadIdx.x >> 6, lane = threadIdx.x & 63;
  const long rowg = (long)blockIdx.x * 4 + wid;
  const int i = (int)(rowg & 127);
  const float* srow = S + rowg * 128;
  u16* prow = P + rowg * 128;
  if (i >= 100) { prow[lane] = 0; prow[lane + 64] = 0; return; }
  const int jmax = (i + 1 < 99) ? i + 1 : 99;          // tril(k=1): j <= i+1, j < 100
  float s0 = srow[lane], s1 = srow[lane + 64];
  bool v0 = lane <= jmax, v1 = (lane + 64) <= jmax;
  float m = fmaxf(v0 ? s0 : -3e38f, v1 ? s1 : -3e38f);
#pragma unroll
  for (int off = 32; off; off >>= 1) m = fmaxf(m, __shfl_xor(m, off));
  float e0 = v0 ? __expf(s0 - m) : 0.f;
  float e1 = v1 ? __expf(s1 - m) : 0.f;
  float sum = e0 + e1;
#pragma unroll
  for (int off = 32; off; off >>= 1) sum += __shfl_xor(sum, off);
  float rs = 1.f / sum;
  prow[lane] = f2bf(e0 * rs);
  prow[lane + 64] = f2bf(e1 * rs);
}

// transpose-cast fp32 W[K][N] -> bf16 Wt[N][K]
__launch_bounds__(256)
__global__ void transpose_cast_w(const float* __restrict__ W, u16* __restrict__ Wt,
                                 int K, int N) {
  __shared__ __align__(16) float t[64][68];
  const int tid = threadIdx.x;
  const int n0 = blockIdx.x * 64, k0 = blockIdx.y * 64;
#pragma unroll
  for (int it = 0; it < 4; ++it) {
    int c = it * 256 + tid;
    int r = c >> 4, cc = (c & 15) * 4;
    f32x4 v = *(const f32x4*)&W[(long)(k0 + r) * N + n0 + cc];
    *(f32x4*)&t[r][cc] = v;
  }
  __syncthreads();
#pragma unroll
  for (int it = 0; it < 4; ++it) {
    int c = it * 256 + tid;
    int n = c >> 4, kk = (c & 15) * 4;
    u16x4 o;
#pragma unroll
    for (int j = 0; j < 4; ++j) o[j] = f2bf(t[kk + j][n]);
    *(u16x4*)&Wt[(long)(n0 + n) * K + k0 + kk] = o;
  }
}

__launch_bounds__(256)
__global__ void cast_f32_to_bf16(const float* __restrict__ in, u16* __restrict__ out, long n4) {
  for (long i = (long)blockIdx.x * 256 + threadIdx.x; i < n4; i += (long)gridDim.x * 256) {
    f32x4 v = *(const f32x4*)&in[i * 4];
    u16x4 o;
#pragma unroll
    for (int j = 0; j < 4; ++j) o[j] = f2bf(v[j]);
    *(u16x4*)&out[i * 4] = o;
  }
}

// concat 3x2048 f32 bias vectors -> one [6144]
__launch_bounds__(256)
__global__ void concat_bias(const float* __restrict__ a, const float* __restrict__ b,
                            const float* __restrict__ c, float* __restrict__ o) {
  int i = blockIdx.x * 256 + threadIdx.x;   // < 6144
  o[i] = i < 2048 ? a[i] : (i < 4096 ? b[i - 2048] : c[i - 4096]);
}

// V view [CH*100][vstride] bf16 -> Vt [CH][2048][128] bf16 (zero-padded s>=100)
__launch_bounds__(256)
__global__ void transpose_v64(const u16* __restrict__ V, u16* __restrict__ Vt, int vstride) {
  __shared__ __align__(16) u16 t[64][72];
  const int tid = threadIdx.x;
  const int h0 = blockIdx.x * 64, s0 = blockIdx.y * 64, b = blockIdx.z;
#pragma unroll
  for (int it = 0; it < 2; ++it) {
    int c = it * 256 + tid;
    int s = c >> 3, hh = (c & 7) * 8;
    u16x8 v = {0, 0, 0, 0, 0, 0, 0, 0};
    if (s0 + s < 100) v = *(const u16x8*)&V[((long)b * 100 + s0 + s) * vstride + h0 + hh];
    *(u16x8*)&t[s][hh] = v;
  }
  __syncthreads();
#pragma unroll
  for (int it = 0; it < 2; ++it) {
    int c = it * 256 + tid;
    int h = c >> 3, ss = (c & 7) * 8;
    u16x8 o;
#pragma unroll
    for (int j = 0; j < 8; ++j) o[j] = t[ss + j][h];
    *(u16x8*)&Vt[((long)b * 2048 + h0 + h) * 128 + s0 + ss] = o;
  }
}

__launch_bounds__(256)
__global__ void ln_stats(const float* __restrict__ y, float* __restrict__ stats) {
  __shared__ float rs[256], rq[256];
  const int b = blockIdx.x, tid = threadIdx.x;
  const float* yb = y + (long)b * 51200;
  float s = 0.f, q = 0.f;
  for (int i = tid; i < 51200; i += 256) { float v = yb[i]; s += v; q += v * v; }
  rs[tid] = s; rq[tid] = q;
  __syncthreads();
  for (int off = 128; off; off >>= 1) {
    if (tid < off) { rs[tid] += rs[tid + off]; rq[tid] += rq[tid + off]; }
    __syncthreads();
  }
  if (tid == 0) {
    float mean = rs[0] * (1.f / 51200.f);
    float var = rq[0] * (1.f / 51200.f) - mean * mean;
    stats[b * 2] = mean;
    stats[b * 2 + 1] = rsqrtf(var + 1e-5f);
  }
}

__launch_bounds__(256)
__global__ void ln_apply(float* __restrict__ y, const float* __restrict__ stats) {
  const long i4 = (long)blockIdx.x * 256 + threadIdx.x;  // < 3276800
  const int b = (int)(i4 / 12800);
  float mu = stats[b * 2], rstd = stats[b * 2 + 1];
  f32x4 v = *(const f32x4*)&y[i4 * 4];
#pragma unroll
  for (int j = 0; j < 4; ++j) v[j] = (v[j] - mu) * rstd;
  *(f32x4*)&y[i4 * 4] = v;
}

extern "C" void kernel_launch(void* const* d_in, const int* in_sizes, int n_in,
                              void* d_out, int out_size, void* d_ws, size_t ws_size,
                              hipStream_t stream) {
  const float* x    = (const float*)d_in[0];
  const float* W_w  = (const float*)d_in[1];
  const float* W_b  = (const float*)d_in[2];
  const float* WK_w = (const float*)d_in[3];
  const float* WK_b = (const float*)d_in[4];
  const float* WQ_w = (const float*)d_in[5];
  const float* WQ_b = (const float*)d_in[6];
  const float* WV_w = (const float*)d_in[7];
  const float* WV_b = (const float*)d_in[8];
  const float* W2_w = (const float*)d_in[9];
  const float* W2_b = (const float*)d_in[10];
  float* out = (float*)d_out;

  // ---- workspace-adaptive batch chunking ----
  const size_t FIXED = 26214400ull + 25165824ull + 2097152ull + 2097152ull + 131072ull;
  const size_t PERB = 2260992ull;
  int CH = 256;
  if (ws_size == 0) CH = 32;
  else { while (CH > 4 && FIXED + (size_t)CH * PERB + 4096 > ws_size) CH >>= 1; }
  const int NCH = 256 / CH;
  const int CHR = CH * 100;                    // rows per chunk
  const int GX = (CHR + 127) / 128;            // 128-tiles per chunk
  const int MT256 = (CHR + 255) / 256;         // 256-tiles per chunk

  char* p = (char*)d_ws;
  auto carve = [&](size_t bytes) { char* r = p; p += (bytes + 255) & ~(size_t)255; return r; };
  u16* xb     = (u16*)carve(26214400);                // x bf16 [25600][512]
  u16* W1t    = (u16*)carve(2097152);                 // [2048][512]
  u16* WKQVt  = (u16*)carve(25165824);                // [6144][2048]  (K|Q|V)
  u16* W2t    = (u16*)carve(2097152);                 // [512][2048]
  float* bkqv = (float*)carve(24576);                 // [6144]
  float* stats = (float*)carve(2048);
  u16* h    = (u16*)carve((size_t)CH * 409600);       // h bf16 [CHR][2048]; reused as o
  u16* KQV  = (u16*)carve((size_t)CH * 1228800);      // [CHR][6144]  K|Q|V strided views
  float* sc = (float*)carve((size_t)CH * 65536);      // scores f32 [CH][128][128]
  u16* P    = (u16*)carve((size_t)CH * 32768);        // P bf16 [CH][128][128]
  u16* Vt   = (u16*)carve((size_t)CH * 524288);       // [CH][2048][128]

  cast_f32_to_bf16<<<2048, 256, 0, stream>>>(x, xb, 3276800);
  transpose_cast_w<<<dim3(32, 8),  256, 0, stream>>>(W_w,  W1t, 512, 2048);
  transpose_cast_w<<<dim3(32, 32), 256, 0, stream>>>(WK_w, WKQVt,               2048, 2048);
  transpose_cast_w<<<dim3(32, 32), 256, 0, stream>>>(WQ_w, WKQVt + 2048 * 2048, 2048, 2048);
  transpose_cast_w<<<dim3(32, 32), 256, 0, stream>>>(WV_w, WKQVt + 4096 * 2048, 2048, 2048);
  transpose_cast_w<<<dim3(8, 32),  256, 0, stream>>>(W2_w, W2t, 2048, 512);
  concat_bias<<<24, 256, 0, stream>>>(WK_b, WQ_b, WV_b, bkqv);

  for (int c = 0; c < NCH; ++c) {
    const u16* xc = xb + (size_t)c * CHR * 512;
    const float* xf = x + (size_t)c * CHR * 512;
    float* outc = out + (size_t)c * CHR * 512;

    // h = relu(xc @ W + b)   M=CHR N=2048 K=512
    gemm_bt<0><<<dim3(GX, 16, 1), 256, 0, stream>>>(xc, 512, 0, CHR - 1, W1t, 512, 0, 2047,
                                                    h, 2048, 0, CHR, W_b, nullptr, 512, 1.f);
    // KQV = h @ [WK|WQ|WV] + b   M=CHR N=6144 K=2048  (256^2 reg-dbuf pipeline)
    gemm256_kqv<<<MT256 * 24, 512, 131072, stream>>>(h, 2048, WKQVt, 2048,
                                                     KQV, 6144, bkqv, CHR, 2048, 24);
    // scores[b] = Q[b] @ K[b]^T / sqrt(512)   batched over CH (strided views into KQV)
    gemm_bt<2><<<dim3(1, 1, CH), 256, 0, stream>>>(KQV + 2048, 6144, 100, CHR - 1,
                                                   KQV,        6144, 100, CHR - 1,
                                                   sc, 128, 128, 1 << 30, nullptr, nullptr,
                                                   2048, 0.044194173824159216f);
    softmax_rows<<<CH * 32, 256, 0, stream>>>(sc, P);
    transpose_v64<<<dim3(32, 2, CH), 256, 0, stream>>>(KQV + 4096, Vt, 6144);
    // o[b] = P[b] @ Vt[b]^T   batched, N=2048, K=128 (o overwrites h)
    gemm_bt<3><<<dim3(1, 16, CH), 256, 0, stream>>>(P, 128, 128, CH * 128 - 1, Vt, 128, 2048,
                                                    CH * 2048 - 1, h, 2048, 100, 100,
                                                    nullptr, nullptr, 128, 1.f);
    // y = o @ W2 + b2 + x   M=CHR N=512 K=2048  (f32 out)
    gemm_bt<4><<<dim3(GX, 4, 1), 256, 0, stream>>>(h, 2048, 0, CHR - 1, W2t, 2048, 0, 511,
                                                   outc, 512, 0, CHR, W2_b, xf, 2048, 1.f);
  }

  ln_stats<<<256, 256, 0, stream>>>(out, stats);
  ln_apply<<<12800, 256, 0, stream>>>(out, stats);
}